// Round 10
// baseline (381.046 us; speedup 1.0000x reference)
//
#include <hip/hip_runtime.h>
#include <stdint.h>

#define NB 2
#define NSQ 2048
#define NSK 2048
#define ND 1024
#define NH 16
#define NDH 64

typedef unsigned short u16;
typedef unsigned int u32;
typedef __bf16 bf16x8_t __attribute__((ext_vector_type(8)));
typedef float f32x4_t __attribute__((ext_vector_type(4)));
typedef u32 u32x4_t __attribute__((ext_vector_type(4)));
typedef short s16x4 __attribute__((ext_vector_type(4)));
typedef u32 u32x2_t __attribute__((ext_vector_type(2)));

#define AS1 __attribute__((address_space(1)))
#define AS3 __attribute__((address_space(3)))

__device__ __forceinline__ float bf2f(u16 u) {
    union { float f; u32 i; } v; v.i = ((u32)u) << 16; return v.f;
}
__device__ __forceinline__ u16 f2bf(float x) {
    union { float f; u32 i; } v; v.f = x;
    u32 r = v.i + 0x7fffu + ((v.i >> 16) & 1u);
    return (u16)(r >> 16);
}
__device__ __forceinline__ u32 fbits(float x) {
    union { float f; u32 i; } v; v.f = x; return v.i;
}
__device__ __forceinline__ float fexp2(float x) {
#if __has_builtin(__builtin_amdgcn_exp2f)
    return __builtin_amdgcn_exp2f(x);   // raw v_exp_f32 (base-2)
#else
    return exp2f(x);
#endif
}
// 16x16x16 bf16 MFMA: A/B = 4 bf16 per lane (k = quad*4 + j) — matches the
// QK^T C-fragment key grouping, so P feeds PV with NO cross-lane movement.
__device__ __forceinline__ f32x4_t mfma16(s16x4 a, s16x4 b, f32x4_t c) {
#if __has_builtin(__builtin_amdgcn_mfma_f32_16x16x16bf16_1k)
    return __builtin_amdgcn_mfma_f32_16x16x16bf16_1k(a, b, c, 0, 0, 0);
#else
    asm("v_mfma_f32_16x16x16_bf16 %0, %1, %2, %0" : "+v"(c) : "v"(a), "v"(b));
    return c;
#endif
}
// wave-uniform dtype detect: all lanes read the same first 512B of Q (L2-hot);
// f32 inputs -> low u16s are mantissa bits, virtually surely "exp">=0x8D.
__device__ __forceinline__ int detect_f32(const u16* __restrict__ Q) {
    uint2 x = ((const uint2*)Q)[threadIdx.x & 63];
    u16 a0 = x.x & 0xffff, a1 = x.x >> 16, a2 = x.y & 0xffff, a3 = x.y >> 16;
    bool big = (((a0 >> 7) & 0xff) >= 0x8D) || (((a1 >> 7) & 0xff) >= 0x8D) ||
               (((a2 >> 7) & 0xff) >= 0x8D) || (((a3 >> 7) & 0xff) >= 0x8D);
    return __any(big);   // 1 = f32 inputs, 0 = bf16 inputs (wave-uniform)
}

// ---------------------------------------------------------------- fused prep
// Block roles by blockIdx.x:
//   [0, 8192)            : input LN  (row = bx); gamma/beta read RAW
//   [8192, 8192+4106)    : param canonicalization (weights + vectors -> bf16)
//   [12298, 12300)       : key index compaction (per batch) + qcnt zeroing
#define PREP_LN   (2 * NB * NSQ)          // 8192
#define PREP_CVT  4106
__global__ __launch_bounds__(256) void prep_kernel(
    const void* __restrict__ Q, const void* __restrict__ K,
    const int* __restrict__ pad_mask,
    const void* __restrict__ Wq, const void* __restrict__ Wk,
    const void* __restrict__ Wv, const void* __restrict__ Wo,
    const void* __restrict__ vbq, const void* __restrict__ vbk,
    const void* __restrict__ vbv, const void* __restrict__ vbo,
    const void* __restrict__ g0, const void* __restrict__ b0,
    const void* __restrict__ g1, const void* __restrict__ b1,
    const void* __restrict__ g2, const void* __restrict__ b2,
    u16* __restrict__ Wc, u16* __restrict__ Vc,
    int* __restrict__ idx, int* __restrict__ cnt, int* __restrict__ qcnt,
    u16* __restrict__ Qn, u16* __restrict__ Kn)
{
    int bx = blockIdx.x;
    int t  = threadIdx.x;

    if (bx < PREP_LN) {
        // ---------------- input LN ----------------
        int flag = detect_f32((const u16*)Q);
        int row = bx;
        const void* x; const void *gv, *bv; u16* y;
        size_t roff;
        if (row < NB * NSQ) {
            x = Q; roff = (size_t)row * ND;
            gv = g0; bv = b0;
            y = Qn + roff;
        } else {
            int r2 = row - NB * NSQ;
            x = K; roff = (size_t)r2 * ND;
            gv = g1; bv = b1;
            y = Kn + roff;
        }
        float v0, v1, v2, v3, gg0, gg1, gg2, gg3, bb0, bb1, bb2, bb3;
        if (flag) {
            float4 xv = ((const float4*)x)[roff / 4 + t];
            v0 = xv.x; v1 = xv.y; v2 = xv.z; v3 = xv.w;
            float4 G = ((const float4*)gv)[t];
            float4 Bv = ((const float4*)bv)[t];
            gg0 = G.x; gg1 = G.y; gg2 = G.z; gg3 = G.w;
            bb0 = Bv.x; bb1 = Bv.y; bb2 = Bv.z; bb3 = Bv.w;
        } else {
            uint2 ux = ((const uint2*)x)[roff / 4 + t];
            v0 = bf2f(ux.x & 0xffff); v1 = bf2f(ux.x >> 16);
            v2 = bf2f(ux.y & 0xffff); v3 = bf2f(ux.y >> 16);
            uint2 G = ((const uint2*)gv)[t];
            uint2 Bv = ((const uint2*)bv)[t];
            gg0 = bf2f(G.x & 0xffff); gg1 = bf2f(G.x >> 16);
            gg2 = bf2f(G.y & 0xffff); gg3 = bf2f(G.y >> 16);
            bb0 = bf2f(Bv.x & 0xffff); bb1 = bf2f(Bv.x >> 16);
            bb2 = bf2f(Bv.y & 0xffff); bb3 = bf2f(Bv.y >> 16);
        }
        float s1 = v0 + v1 + v2 + v3;
        float s2 = v0*v0 + v1*v1 + v2*v2 + v3*v3;
#pragma unroll
        for (int off = 32; off >= 1; off >>= 1) {
            s1 += __shfl_xor(s1, off);
            s2 += __shfl_xor(s2, off);
        }
        __shared__ float r1[4], r2[4];
        int wave = t >> 6;
        if ((t & 63) == 0) { r1[wave] = s1; r2[wave] = s2; }
        __syncthreads();
        float t1 = r1[0] + r1[1] + r1[2] + r1[3];
        float t2 = r2[0] + r2[1] + r2[2] + r2[3];
        float mean = t1 * (1.0f / ND);
        float var  = t2 * (1.0f / ND) - mean * mean;
        float rstd = rsqrtf(var + 1e-5f);
        float y0 = (v0 - mean) * rstd * gg0 + bb0;
        float y1 = (v1 - mean) * rstd * gg1 + bb1;
        float y2 = (v2 - mean) * rstd * gg2 + bb2;
        float y3 = (v3 - mean) * rstd * gg3 + bb3;
        uint2 o;
        o.x = (u32)f2bf(y0) | ((u32)f2bf(y1) << 16);
        o.y = (u32)f2bf(y2) | ((u32)f2bf(y3) << 16);
        ((uint2*)y)[t] = o;
    } else if (bx < PREP_LN + PREP_CVT) {
        // ---------------- param canonicalization ----------------
        int flag = detect_f32((const u16*)Q);
        int blk = bx - PREP_LN;
        const void* src;
        u16* dst;
        size_t srcoff;
        if (blk < 4096) {
            int w = blk >> 10;
            src = (w == 0) ? Wq : (w == 1) ? Wk : (w == 2) ? Wv : Wo;
            srcoff = (size_t)(blk & 1023) * 1024;
            dst = Wc + (size_t)w * 1024 * 1024 + srcoff;
        } else {
            int v = blk - 4096;
            src = (v == 0) ? vbq : (v == 1) ? vbk : (v == 2) ? vbv : (v == 3) ? vbo :
                  (v == 4) ? g0  : (v == 5) ? b0  : (v == 6) ? g1  : (v == 7) ? b1 :
                  (v == 8) ? g2  : b2;
            srcoff = 0;
            dst = Vc + (size_t)v * 1024;
        }
        u32 lo, hi;
        if (flag) {
            float4 x = ((const float4*)src)[srcoff / 4 + t];
            lo = (u32)f2bf(x.x) | ((u32)f2bf(x.y) << 16);
            hi = (u32)f2bf(x.z) | ((u32)f2bf(x.w) << 16);
        } else {
            uint2 x = ((const uint2*)src)[srcoff / 4 + t];
            lo = x.x; hi = x.y;
        }
        uint2 o; o.x = lo; o.y = hi;
        ((uint2*)dst)[t] = o;
    } else {
        // ---------------- key index compaction + qcnt zero ----------------
        int b = bx - (PREP_LN + PREP_CVT);
        if (t < 32) qcnt[b * 32 + t] = 0;   // attn completion counters
        const int* m = pad_mask + b * NSK;
        int loc[8]; int s = 0;
#pragma unroll
        for (int i = 0; i < 8; ++i) { loc[i] = (m[t * 8 + i] != 0); s += loc[i]; }
        __shared__ int ps[256];
        ps[t] = s;
        __syncthreads();
        for (int off = 1; off < 256; off <<= 1) {
            int v = (t >= off) ? ps[t - off] : 0;
            __syncthreads();
            ps[t] += v;
            __syncthreads();
        }
        int run = ps[t] - s;   // exclusive prefix
#pragma unroll
        for (int i = 0; i < 8; ++i)
            if (loc[i]) idx[b * NSK + run++] = t * 8 + i;
        if (t == 255) cnt[b] = ps[255];
    }
}

// ---------------------------------------------------------------- fused 4x GEMM
// (round-6 known-good) 256x256 tile, 8 waves (2M x 4N), BK=32, ring-4 LDS.
// ONE barrier per K-tile; counted vmcnt(8); drains 8->4->0 at t=29/30.
// T2 both-sides swizzle; bijective XCD swizzle.
// z=0: (Qn@Wq^T+bq)*log2e/32 -> Q1 ; z=1: Kn@Wk^T+bk -> K1
// z=2: Kn@Wv^T+bv -> V1 (row layout) ; z=3: relu(Qn@Wo^T+bo) -> R
__global__ __launch_bounds__(512, 2) void gemm4_kernel(
    const u16* __restrict__ Qn, const u16* __restrict__ Kn,
    const u16* __restrict__ Wc, const u16* __restrict__ Vc,
    u16* __restrict__ Q1, u16* __restrict__ K1, u16* __restrict__ V1,
    u16* __restrict__ R)
{
    // XCD-aware remap of (bx,by,bz): lin increments x fastest (dispatch order)
    int lin = blockIdx.x + 16 * blockIdx.y + 64 * blockIdx.z;
    int u   = (lin & 7) * 32 + (lin >> 3);
    int bx  = u & 15;
    int by  = (u >> 4) & 3;
    int z   = u >> 6;

    const u16* X    = (z == 0 || z == 3) ? Qn : Kn;
    const u16* W    = Wc + (size_t)z * 1024 * 1024;
    const u16* bias = Vc + (size_t)z * 1024;

    __shared__ u16 sm[4][2][256 * 32];   // 128 KiB: 4 slots x {A,B} x 16 KiB

    int tid  = threadIdx.x;
    int wave = tid >> 6, lane = tid & 63;
    int wm = wave >> 2, wn = wave & 3;          // 2M x 4N wave grid
    int quad = lane >> 4, l4 = lane & 15;
    int m0 = bx * 256;
    int n0 = by * 256;

    // staging: linear LDS dest (gload_lds requirement), pre-swizzled source
    int srow   = wave * 16 + (lane >> 2);                // rows 0..127 (inst0)
    int schunk = (lane & 3) ^ ((srow >> 1) & 3);         // inv-swizzle source
    const u16* gA = X + (size_t)(m0 + srow) * ND + schunk * 8;
    const u16* gB = W + (size_t)(n0 + srow) * ND + schunk * 8;

#define STAGE_A(t_) do { int s_ = (t_) & 3; \
    __builtin_amdgcn_global_load_lds((const AS1 u32*)(gA + (t_) * 32), \
        (AS3 u32*)(&sm[s_][0][wave * 512]), 16, 0, 0); \
    __builtin_amdgcn_global_load_lds((const AS1 u32*)(gA + (t_) * 32 + (size_t)128 * ND), \
        (AS3 u32*)(&sm[s_][0][4096 + wave * 512]), 16, 0, 0); \
} while (0)
#define STAGE_B(t_) do { int s_ = (t_) & 3; \
    __builtin_amdgcn_global_load_lds((const AS1 u32*)(gB + (t_) * 32), \
        (AS3 u32*)(&sm[s_][1][wave * 512]), 16, 0, 0); \
    __builtin_amdgcn_global_load_lds((const AS1 u32*)(gB + (t_) * 32 + (size_t)128 * ND), \
        (AS3 u32*)(&sm[s_][1][4096 + wave * 512]), 16, 0, 0); \
} while (0)

    // fragment read addressing; swizzled chunk is lane-constant:
    // row = 16*base + l4  ->  (row>>1)&3 == (l4>>1)&3
    int fch   = (quad ^ ((l4 >> 1) & 3)) * 8;
    int aoffb = (wm * 128 + l4) * 32 + fch;   // + mf*512
    int boffb = (wn * 64  + l4) * 32 + fch;   // + nf*512

    f32x4_t acc[8][4];
#pragma unroll
    for (int i = 0; i < 8; ++i)
#pragma unroll
        for (int j = 0; j < 4; ++j)
            acc[i][j] = (f32x4_t){0.f, 0.f, 0.f, 0.f};

    // prologue: 3 K-tiles in flight, validate tile 0 (8 loads may stay out)
    STAGE_A(0); STAGE_B(0);
    STAGE_A(1); STAGE_B(1);
    STAGE_A(2); STAGE_B(2);
    asm volatile("s_waitcnt vmcnt(8)" ::: "memory");
    __builtin_amdgcn_s_barrier();
    __builtin_amdgcn_sched_barrier(0);

    for (int t = 0; t < 32; ++t) {
        const u16* a = &sm[t & 3][0][0];
        const u16* b = &sm[t & 3][1][0];
        bf16x8_t bf[4], af[4], ah[4];

        // 12 ds_read_b128 (tile t) — compiler interleaves with MFMA via lgkmcnt
#pragma unroll
        for (int nf = 0; nf < 4; ++nf)
            bf[nf] = *(const bf16x8_t*)(b + boffb + nf * 512);
#pragma unroll
        for (int mf = 0; mf < 4; ++mf)
            af[mf] = *(const bf16x8_t*)(a + aoffb + mf * 512);
#pragma unroll
        for (int mf = 0; mf < 4; ++mf)
            ah[mf] = *(const bf16x8_t*)(a + aoffb + (mf + 4) * 512);

        // stage tile t+3 into slot (t-1)&3 (WAR-safe past last barrier)
        if (t < 29) { STAGE_A(t + 3); STAGE_B(t + 3); }

        __builtin_amdgcn_s_setprio(1);
#pragma unroll
        for (int mf = 0; mf < 4; ++mf)
#pragma unroll
            for (int nf = 0; nf < 4; ++nf)
                acc[mf][nf] = __builtin_amdgcn_mfma_f32_16x16x32_bf16(
                    af[mf], bf[nf], acc[mf][nf], 0, 0, 0);
#pragma unroll
        for (int mf = 0; mf < 4; ++mf)
#pragma unroll
            for (int nf = 0; nf < 4; ++nf)
                acc[mf + 4][nf] = __builtin_amdgcn_mfma_f32_16x16x32_bf16(
                    ah[mf], bf[nf], acc[mf + 4][nf], 0, 0, 0);
        __builtin_amdgcn_s_setprio(0);

        // K-tile boundary: validate tile t+1; keep tiles t+2,t+3 in flight
        if (t < 29)       asm volatile("s_waitcnt vmcnt(8)" ::: "memory");
        else if (t == 29) asm volatile("s_waitcnt vmcnt(4)" ::: "memory");
        else if (t == 30) asm volatile("s_waitcnt vmcnt(0)" ::: "memory");
        __builtin_amdgcn_s_barrier();
        __builtin_amdgcn_sched_barrier(0);
    }
#undef STAGE_A
#undef STAGE_B

    // epilogue: mf/r outer, nf inner -> line-complete store order
    u16* outp = (z == 0) ? Q1 : (z == 1) ? K1 : (z == 2) ? V1 : R;
    float bv_[4];
#pragma unroll
    for (int nf = 0; nf < 4; ++nf)
        bv_[nf] = bf2f(bias[n0 + wn * 64 + nf * 16 + l4]);
#pragma unroll
    for (int mf = 0; mf < 8; ++mf) {
#pragma unroll
        for (int r = 0; r < 4; ++r) {
            int m = m0 + wm * 128 + mf * 16 + quad * 4 + r;
#pragma unroll
            for (int nf = 0; nf < 4; ++nf) {
                int n = n0 + wn * 64 + nf * 16 + l4;
                float val = acc[mf][nf][r] + bv_[nf];
                if (z == 0) val *= 0.045105964f;   // (1/32) * log2(e)
                if (z == 3) val = fmaxf(val, 0.f);
                outp[(size_t)m * ND + n] = f2bf(val);
            }
        }
    }
}

// ---------------------------------------------------------------- fused gathers
// blockIdx.x < 128: Kc[b][j] = K1[b][idx[j]] (j < cnt; zero-pad to 64-mult)
// else             : Vct[b][h][d][j] = V1[b][idx[j]][h*64+d]
__global__ __launch_bounds__(256) void gather_kernel(
    const u16* __restrict__ K1, const u16* __restrict__ V1,
    const int* __restrict__ idx, const int* __restrict__ cnt,
    u16* __restrict__ Kc, u16* __restrict__ Vct)
{
    int b = blockIdx.y;
    int c = cnt[b];
    int cPad = (c + 63) & ~63;
    int tid = threadIdx.x;

    if (blockIdx.x < 128) {
        // ---------------- K gather ----------------
        int jb = blockIdx.x * 16;
        if (jb >= cPad) return;
        int row = tid >> 4;          // 0..15
        int seg = tid & 15;          // 8 uint4 each
        int j = jb + row;
        if (j >= cPad) return;
        bool z = (j >= c);
        const u16* src = z ? (const u16*)0
            : K1 + ((size_t)b * NSK + idx[(size_t)b * NSK + j]) * ND;
        u16* dst = Kc + ((size_t)b * NSK + j) * ND;
#pragma unroll
        for (int i = 0; i < 8; ++i) {
            int off = (seg * 8 + i) * 8;
            uint4 v = z ? (uint4){0, 0, 0, 0} : *(const uint4*)(src + off);
            *(uint4*)(dst + off) = v;
        }
    } else {
        // ---------------- V^T gather ----------------
        int lin = blockIdx.x - 128;
        int kb = lin & 31;
        int h  = lin >> 5;
        if (kb * 64 >= cPad) return;
        __shared__ u16 sT[64 * 72];
        {
            int row = tid >> 3, seg = tid & 7;
            int j1 = kb * 64 + row, j2 = j1 + 32;
            uint4 v1 = {0, 0, 0, 0}, v2 = {0, 0, 0, 0};
            if (j1 < c) v1 = *(const uint4*)(V1 +
                ((size_t)b * NSK + idx[(size_t)b * NSK + j1]) * ND + h * NDH + seg * 8);
            if (j2 < c) v2 = *(const uint4*)(V1 +
                ((size_t)b * NSK + idx[(size_t)b * NSK + j2]) * ND + h * NDH + seg * 8);
            *(uint4*)(sT + row * 72 + seg * 8) = v1;
            *(uint4*)(sT + (row + 32) * 72 + seg * 8) = v2;
        }
        __syncthreads();
        int d = tid >> 2, sg = tid & 3;
        u16 buf[16];
#pragma unroll
        for (int i = 0; i < 8; ++i) buf[i]     = sT[(sg * 8 + i) * 72 + d];
#pragma unroll
        for (int i = 0; i < 8; ++i) buf[8 + i] = sT[((sg + 4) * 8 + i) * 72 + d];
        u16* go = Vct + ((size_t)(b * NH + h) * NDH + d) * NSK + kb * 64;
        *(uint4*)(go + sg * 8)       = *(uint4*)buf;
        *(uint4*)(go + (sg + 4) * 8) = *(uint4*)(buf + 8);
    }
}

// ---------------------------------------------------------------- flash attention
// Round-6 known-good body + fused final LN: the LAST head-block to finish a
// (b, q0) 64-row group (device-scope atomic counter, release/acquire fences
// per G16/G12) LayerNorms those rows — one row per wave, 64-lane shuffle
// reduce, no barriers. Removes the separate ln_out dispatch.
__global__ __launch_bounds__(256, 4) void attn_kernel(
    const u16* __restrict__ Q1, const u16* __restrict__ Kc,
    const u16* __restrict__ Vct, const int* __restrict__ cnt,
    u16* __restrict__ R,
    const void* __restrict__ Qraw, const u16* __restrict__ Vc,
    int* __restrict__ qcnt, void* __restrict__ out)
{
    int q0 = blockIdx.x * 64;
    int h  = blockIdx.y;
    int b  = blockIdx.z;

    __shared__ u16 sK[2][64 * 64];
    __shared__ u16 sV[2][64 * 64];

    int tid  = threadIdx.x;
    int wave = tid >> 6, lane = tid & 63;
    int quad = lane >> 4, l4 = lane & 15;
    int lk = lane >> 3, ls = lane & 7;
    int gseg = ls ^ lk;

    int c  = cnt[b];
    int nt = (c + 63) >> 6;

    bf16x8_t qf[2];
    {
        const u16* qp = Q1 + (size_t)(b * NSQ + q0 + wave * 16 + l4) * ND + h * NDH;
        qf[0] = *(const bf16x8_t*)(qp + quad * 8);
        qf[1] = *(const bf16x8_t*)(qp + 32 + quad * 8);
    }

    const u16* kbase = Kc + (size_t)b * NSK * ND + h * NDH;
    const u16* vbase = Vct + (size_t)(b * NH + h) * NDH * NSK;

    const u16* gk0 = kbase + (size_t)(wave * 16 + lk) * ND + gseg * 8;
    const u16* gk1 = gk0 + (size_t)8 * ND;
    const u16* gv0 = vbase + (size_t)(wave * 16 + lk) * NSK + gseg * 8;
    const u16* gv1 = gv0 + (size_t)8 * NSK;

    // K-fragment (x32) swizzled offsets
    int fragOff[2];
#pragma unroll
    for (int kk = 0; kk < 2; ++kk)
        fragOff[kk] = l4 * 64 + (((kk * 4 + quad) ^ (l4 & 7)) * 8);

    // V-fragment (x16) swizzled offsets: keys 16*tm + 4*quad + j, row l4
    int v4off[4];
#pragma unroll
    for (int tm = 0; tm < 4; ++tm)
        v4off[tm] = l4 * 64 + (((2 * tm + (quad >> 1)) ^ (l4 & 7)) * 8)
                  + (quad & 1) * 4;

    float l_run = 0.f;
    f32x4_t acc_o[4];
#pragma unroll
    for (int T = 0; T < 4; ++T) acc_o[T] = (f32x4_t){0.f, 0.f, 0.f, 0.f};

    if (nt > 0) {
        __builtin_amdgcn_global_load_lds((const AS1 u32*)gk0,
            (AS3 u32*)(&sK[0][(wave * 16) * 64]), 16, 0, 0);
        __builtin_amdgcn_global_load_lds((const AS1 u32*)gk1,
            (AS3 u32*)(&sK[0][(wave * 16 + 8) * 64]), 16, 0, 0);
        __builtin_amdgcn_global_load_lds((const AS1 u32*)gv0,
            (AS3 u32*)(&sV[0][(wave * 16) * 64]), 16, 0, 0);
        __builtin_amdgcn_global_load_lds((const AS1 u32*)gv1,
            (AS3 u32*)(&sV[0][(wave * 16 + 8) * 64]), 16, 0, 0);
        gk0 += (size_t)64 * ND; gk1 += (size_t)64 * ND;
        gv0 += 64; gv1 += 64;

        for (int kb = 0; kb < nt; ++kb) {
            __syncthreads();

            if (kb + 1 < nt) {
                int bi = (kb + 1) & 1;
                __builtin_amdgcn_global_load_lds((const AS1 u32*)gk0,
                    (AS3 u32*)(&sK[bi][(wave * 16) * 64]), 16, 0, 0);
                __builtin_amdgcn_global_load_lds((const AS1 u32*)gk1,
                    (AS3 u32*)(&sK[bi][(wave * 16 + 8) * 64]), 16, 0, 0);
                __builtin_amdgcn_global_load_lds((const AS1 u32*)gv0,
                    (AS3 u32*)(&sV[bi][(wave * 16) * 64]), 16, 0, 0);
                __builtin_amdgcn_global_load_lds((const AS1 u32*)gv1,
                    (AS3 u32*)(&sV[bi][(wave * 16 + 8) * 64]), 16, 0, 0);
                gk0 += (size_t)64 * ND; gk1 += (size_t)64 * ND;
                gv0 += 64; gv1 += 64;
            }

            const u16* kt = sK[kb & 1];
            const u16* vt = sV[kb & 1];

            // C-init: 0 for valid keys; -1e9 on tail keys >= cnt
            f32x4_t accs[4];
            if (kb == nt - 1) {
#pragma unroll
                for (int tm = 0; tm < 4; ++tm) {
                    int key = kb * 64 + tm * 16 + quad * 4;
#pragma unroll
                    for (int r = 0; r < 4; ++r)
                        accs[tm][r] = (key + r < c) ? 0.f : -1e9f;
                }
            } else {
#pragma unroll
                for (int tm = 0; tm < 4; ++tm)
                    accs[tm] = (f32x4_t){0.f, 0.f, 0.f, 0.f};
            }
#pragma unroll
            for (int kk = 0; kk < 2; ++kk)
#pragma unroll
                for (int tm = 0; tm < 4; ++tm) {
                    bf16x8_t kf = *(const bf16x8_t*)(kt + tm * 1024 + fragOff[kk]);
                    accs[tm] = __builtin_amdgcn_mfma_f32_16x16x32_bf16(
                        kf, qf[kk], accs[tm], 0, 0, 0);
                }

            // softmax + PV fused: p = exp2(s) (Q pre-scaled by log2e/32);
            // P lane-local -> x16 MFMA directly, no cross-lane movement
            float lsum = 0.f;
#pragma unroll
            for (int tm = 0; tm < 4; ++tm) {
                float p0 = fexp2(accs[tm][0]);
                float p1 = fexp2(accs[tm][1]);
                float p2 = fexp2(accs[tm][2]);
                float p3 = fexp2(accs[tm][3]);
                lsum += (p0 + p1) + (p2 + p3);
                u32 lo = __builtin_amdgcn_perm(fbits(p1), fbits(p0), 0x07060302);
                u32 hi = __builtin_amdgcn_perm(fbits(p3), fbits(p2), 0x07060302);
                s16x4 pf = __builtin_bit_cast(s16x4, (u32x2_t){lo, hi});
#pragma unroll
                for (int T = 0; T < 4; ++T) {
                    s16x4 vf = *(const s16x4*)(vt + T * 1024 + v4off[tm]);
                    acc_o[T] = mfma16(vf, pf, acc_o[T]);
                }
            }
            lsum += __shfl_xor(lsum, 16);
            lsum += __shfl_xor(lsum, 32);
            l_run += lsum;
        }
    }

    // epilogue: O[q][d] = acc_o / l ; R += O1 (uint2 RMW)
    float inv = l_run > 0.f ? 1.f / l_run : 0.f;
    u16* rp = R + (size_t)(b * NSQ + q0 + wave * 16 + l4) * ND + h * NDH;
#pragma unroll
    for (int T = 0; T < 4; ++T) {
        u16* p = rp + T * 16 + quad * 4;
        uint2 o2 = *(const uint2*)p;
        float e0 = acc_o[T][0] * inv + bf2f(o2.x & 0xffff);
        float e1 = acc_o[T][1] * inv + bf2f(o2.x >> 16);
        float e2 = acc_o[T][2] * inv + bf2f(o2.y & 0xffff);
        float e3 = acc_o[T][3] * inv + bf2f(o2.y >> 16);
        uint2 on;
        on.x = (u32)f2bf(e0) | ((u32)f2bf(e1) << 16);
        on.y = (u32)f2bf(e2) | ((u32)f2bf(e3) << 16);
        *(uint2*)p = on;
    }

    // ---- fused final LN: last head-block for (b, q0) LNs the 64 rows ----
    __threadfence();          // release: this block's R stores (all threads)
    __syncthreads();          // no thread's stores may trail the publish
    __shared__ int sdone;
    if (tid == 0)
        sdone = (atomicAdd(&qcnt[b * 32 + blockIdx.x], 1) == NH - 1) ? 1 : 0;
    __syncthreads();
    if (!sdone) return;
    __threadfence();          // acquire: other blocks' R stores visible

    int f = detect_f32((const u16*)Qraw);
    const u16* gg = Vc + 8 * 1024;
    const u16* gb = Vc + 9 * 1024;
#pragma unroll 1
    for (int rr = 0; rr < 16; ++rr) {
        int row = q0 + rr * 4 + wave;        // one row per wave, 16 rounds
        size_t roff = ((size_t)b * NSQ + row) * ND;
        float v[16];
#pragma unroll
        for (int i = 0; i < 4; ++i) {
            size_t u2i = roff / 4 + i * 64 + lane;
            uint2 ur = ((const uint2*)R)[u2i];
            float r0 = bf2f(ur.x & 0xffff), r1 = bf2f(ur.x >> 16);
            float r2 = bf2f(ur.y & 0xffff), r3 = bf2f(ur.y >> 16);
            if (f) {
                float4 xq = ((const float4*)Qraw)[u2i];
                v[i*4+0] = xq.x + r0; v[i*4+1] = xq.y + r1;
                v[i*4+2] = xq.z + r2; v[i*4+3] = xq.w + r3;
            } else {
                uint2 uq = ((const uint2*)Qraw)[u2i];
                v[i*4+0] = bf2f(uq.x & 0xffff) + r0;
                v[i*4+1] = bf2f(uq.x >> 16)    + r1;
                v[i*4+2] = bf2f(uq.y & 0xffff) + r2;
                v[i*4+3] = bf2f(uq.y >> 16)    + r3;
            }
        }
        float s1 = 0.f, s2 = 0.f;
#pragma unroll
        for (int i = 0; i < 16; ++i) { s1 += v[i]; s2 += v[i] * v[i]; }
#pragma unroll
        for (int off = 32; off >= 1; off >>= 1) {
            s1 += __shfl_xor(s1, off);
            s2 += __shfl_xor(s2, off);
        }
        float mean = s1 * (1.0f / ND);
        float var  = s2 * (1.0f / ND) - mean * mean;
        float rstd = rsqrtf(var + 1e-5f);
#pragma unroll
        for (int i = 0; i < 4; ++i) {
            size_t u2i = roff / 4 + i * 64 + lane;
            uint2 ug = ((const uint2*)gg)[i * 64 + lane];
            uint2 ub = ((const uint2*)gb)[i * 64 + lane];
            float y0 = (v[i*4+0] - mean) * rstd * bf2f(ug.x & 0xffff) + bf2f(ub.x & 0xffff);
            float y1 = (v[i*4+1] - mean) * rstd * bf2f(ug.x >> 16)    + bf2f(ub.x >> 16);
            float y2 = (v[i*4+2] - mean) * rstd * bf2f(ug.y & 0xffff) + bf2f(ub.y & 0xffff);
            float y3 = (v[i*4+3] - mean) * rstd * bf2f(ug.y >> 16)    + bf2f(ub.y >> 16);
            if (f) {
                float4 o; o.x = y0; o.y = y1; o.z = y2; o.w = y3;
                ((float4*)out)[u2i] = o;
            } else {
                uint2 o;
                o.x = (u32)f2bf(y0) | ((u32)f2bf(y1) << 16);
                o.y = (u32)f2bf(y2) | ((u32)f2bf(y3) << 16);
                ((uint2*)out)[u2i] = o;
            }
        }
    }
}

// ---------------------------------------------------------------- launch
extern "C" void kernel_launch(void* const* d_in, const int* in_sizes, int n_in,
                              void* d_out, int out_size, void* d_ws, size_t ws_size,
                              hipStream_t stream) {
    const void* Q        = d_in[0];
    const void* K        = d_in[1];
    const int* pad_mask  = (const int*)d_in[2];

    const size_t NEL = (size_t)NB * NSQ * ND;   // 4,194,304
    int* flag = (int*)d_ws;                      // [0] (unused; layout keep)
    int* cnt  = flag + 1;                        // [1..3)
    int* idx  = flag + 4;                        // [4..4100)
    int* qcnt = flag + 4100;                     // [4100..4164) attn counters
    u16* base = (u16*)(flag + 4168);             // 16-byte aligned
    u16* Qn  = base;
    u16* Kn  = Qn + NEL;
    u16* Q1  = Kn + NEL;
    u16* K1  = Q1 + NEL;
    u16* V1  = K1 + NEL;
    u16* R   = V1 + NEL;
    u16* Wc  = R + NEL;
    u16* Vc  = Wc + (size_t)4 * 1024 * 1024;
    u16* Kc  = Qn;                               // aliases Qn (dead after gemm4)
    u16* Vct = Kn;                               // aliases Kn (dead after gemm4)

    prep_kernel<<<dim3(PREP_LN + PREP_CVT + NB), dim3(256), 0, stream>>>(
        Q, K, pad_mask,
        d_in[3], d_in[4], d_in[5], d_in[6],
        d_in[7], d_in[8], d_in[9], d_in[10],
        d_in[11], d_in[12], d_in[13], d_in[14], d_in[15], d_in[16],
        Wc, Vc, idx, cnt, qcnt, Qn, Kn);

    gemm4_kernel<<<dim3(16, 4, 4), dim3(512), 0, stream>>>(
        Qn, Kn, Wc, Vc, Q1, K1, V1, R);

    gather_kernel<<<dim3(128 + 32 * NH, NB), dim3(256), 0, stream>>>(
        K1, V1, idx, cnt, Kc, Vct);

    attn_kernel<<<dim3(NSQ / 64, NH, NB), dim3(256), 0, stream>>>(
        Q1, Kc, Vct, cnt, R, Q, Vc, qcnt, d_out);
}

// Round 11
// 217.277 us; speedup vs baseline: 1.7537x; 1.7537x over previous
//
#include <hip/hip_runtime.h>
#include <stdint.h>

#define NB 2
#define NSQ 2048
#define NSK 2048
#define ND 1024
#define NH 16
#define NDH 64

typedef unsigned short u16;
typedef unsigned int u32;
typedef __bf16 bf16x8_t __attribute__((ext_vector_type(8)));
typedef float f32x4_t __attribute__((ext_vector_type(4)));
typedef u32 u32x4_t __attribute__((ext_vector_type(4)));
typedef short s16x4 __attribute__((ext_vector_type(4)));
typedef u32 u32x2_t __attribute__((ext_vector_type(2)));

#define AS1 __attribute__((address_space(1)))
#define AS3 __attribute__((address_space(3)))

__device__ __forceinline__ float bf2f(u16 u) {
    union { float f; u32 i; } v; v.i = ((u32)u) << 16; return v.f;
}
__device__ __forceinline__ u16 f2bf(float x) {
    union { float f; u32 i; } v; v.f = x;
    u32 r = v.i + 0x7fffu + ((v.i >> 16) & 1u);
    return (u16)(r >> 16);
}
__device__ __forceinline__ u32 fbits(float x) {
    union { float f; u32 i; } v; v.f = x; return v.i;
}
__device__ __forceinline__ float fexp2(float x) {
#if __has_builtin(__builtin_amdgcn_exp2f)
    return __builtin_amdgcn_exp2f(x);   // raw v_exp_f32 (base-2)
#else
    return exp2f(x);
#endif
}
// 16x16x16 bf16 MFMA: A/B = 4 bf16 per lane (k = quad*4 + j) — matches the
// QK^T C-fragment key grouping, so P feeds PV with NO cross-lane movement.
__device__ __forceinline__ f32x4_t mfma16(s16x4 a, s16x4 b, f32x4_t c) {
#if __has_builtin(__builtin_amdgcn_mfma_f32_16x16x16bf16_1k)
    return __builtin_amdgcn_mfma_f32_16x16x16bf16_1k(a, b, c, 0, 0, 0);
#else
    asm("v_mfma_f32_16x16x16_bf16 %0, %1, %2, %0" : "+v"(c) : "v"(a), "v"(b));
    return c;
#endif
}
// wave-uniform dtype detect: all lanes read the same first 512B of Q (L2-hot);
// f32 inputs -> low u16s are mantissa bits, virtually surely "exp">=0x8D.
__device__ __forceinline__ int detect_f32(const u16* __restrict__ Q) {
    uint2 x = ((const uint2*)Q)[threadIdx.x & 63];
    u16 a0 = x.x & 0xffff, a1 = x.x >> 16, a2 = x.y & 0xffff, a3 = x.y >> 16;
    bool big = (((a0 >> 7) & 0xff) >= 0x8D) || (((a1 >> 7) & 0xff) >= 0x8D) ||
               (((a2 >> 7) & 0xff) >= 0x8D) || (((a3 >> 7) & 0xff) >= 0x8D);
    return __any(big);   // 1 = f32 inputs, 0 = bf16 inputs (wave-uniform)
}

// ---------------------------------------------------------------- fused prep
// Block roles by blockIdx.x:
//   [0, 4096)            : Q input LN (row = bx)
//   [4096, 8192)         : K input LN + COMPACTION — each block computes its
//                          row's destination (prefix-count of mask, L2-hot
//                          8KB) and writes LN(K[row]) to Knc[dst]; masked
//                          rows exit early. Kn is compact after prep.
//   [8192, 8192+4106)    : param canonicalization (weights + vectors -> bf16)
//   [12298, 12300)       : cnt[b] + zero Knc pad rows [c, cPad)
#define PREP_LN   (2 * NB * NSQ)          // 8192
#define PREP_CVT  4106
__global__ __launch_bounds__(256) void prep_kernel(
    const void* __restrict__ Q, const void* __restrict__ K,
    const int* __restrict__ pad_mask,
    const void* __restrict__ Wq, const void* __restrict__ Wk,
    const void* __restrict__ Wv, const void* __restrict__ Wo,
    const void* __restrict__ vbq, const void* __restrict__ vbk,
    const void* __restrict__ vbv, const void* __restrict__ vbo,
    const void* __restrict__ g0, const void* __restrict__ b0,
    const void* __restrict__ g1, const void* __restrict__ b1,
    const void* __restrict__ g2, const void* __restrict__ b2,
    u16* __restrict__ Wc, u16* __restrict__ Vc,
    int* __restrict__ cnt,
    u16* __restrict__ Qn, u16* __restrict__ Kn)
{
    int bx = blockIdx.x;
    int t  = threadIdx.x;

    if (bx < PREP_LN) {
        __shared__ float r1[4], r2[4];
        __shared__ int r0[4];
        int flag = detect_f32((const u16*)Q);
        int wave = t >> 6;
        bool isQ = bx < NB * NSQ;
        int pc = 0;
        const void* x; const void *gv, *bv;
        size_t roff;
        int bb_ = 0;
        if (isQ) {
            x = Q; roff = (size_t)bx * ND;
            gv = g0; bv = b0;
        } else {
            int r2_ = bx - NB * NSQ;
            bb_ = r2_ >> 11;
            int lr = r2_ & 2047;
            const int* mb = pad_mask + (size_t)bb_ * NSK;
            if (mb[lr] == 0) return;   // dropped key row (uniform)
#pragma unroll
            for (int i = 0; i < 8; ++i) {
                int j = t * 8 + i;
                pc += (j < lr && mb[j] != 0) ? 1 : 0;
            }
            x = K; roff = ((size_t)bb_ * NSK + lr) * ND;
            gv = g1; bv = b1;
        }
        float v0, v1, v2, v3, gg0, gg1, gg2, gg3, bb0, bb1, bb2, bb3;
        if (flag) {
            float4 xv = ((const float4*)x)[roff / 4 + t];
            v0 = xv.x; v1 = xv.y; v2 = xv.z; v3 = xv.w;
            float4 G = ((const float4*)gv)[t];
            float4 Bv = ((const float4*)bv)[t];
            gg0 = G.x; gg1 = G.y; gg2 = G.z; gg3 = G.w;
            bb0 = Bv.x; bb1 = Bv.y; bb2 = Bv.z; bb3 = Bv.w;
        } else {
            uint2 ux = ((const uint2*)x)[roff / 4 + t];
            v0 = bf2f(ux.x & 0xffff); v1 = bf2f(ux.x >> 16);
            v2 = bf2f(ux.y & 0xffff); v3 = bf2f(ux.y >> 16);
            uint2 G = ((const uint2*)gv)[t];
            uint2 Bv = ((const uint2*)bv)[t];
            gg0 = bf2f(G.x & 0xffff); gg1 = bf2f(G.x >> 16);
            gg2 = bf2f(G.y & 0xffff); gg3 = bf2f(G.y >> 16);
            bb0 = bf2f(Bv.x & 0xffff); bb1 = bf2f(Bv.x >> 16);
            bb2 = bf2f(Bv.y & 0xffff); bb3 = bf2f(Bv.y >> 16);
        }
        float s1 = v0 + v1 + v2 + v3;
        float s2 = v0*v0 + v1*v1 + v2*v2 + v3*v3;
#pragma unroll
        for (int off = 32; off >= 1; off >>= 1) {
            s1 += __shfl_xor(s1, off);
            s2 += __shfl_xor(s2, off);
            pc += __shfl_xor(pc, off);
        }
        if ((t & 63) == 0) { r1[wave] = s1; r2[wave] = s2; r0[wave] = pc; }
        __syncthreads();
        float t1 = r1[0] + r1[1] + r1[2] + r1[3];
        float t2 = r2[0] + r2[1] + r2[2] + r2[3];
        float mean = t1 * (1.0f / ND);
        float var  = t2 * (1.0f / ND) - mean * mean;
        float rstd = rsqrtf(var + 1e-5f);
        u16* y;
        if (isQ) {
            y = Qn + (size_t)bx * ND;
        } else {
            int dst = r0[0] + r0[1] + r0[2] + r0[3];
            y = Kn + ((size_t)bb_ * NSK + dst) * ND;
        }
        float y0 = (v0 - mean) * rstd * gg0 + bb0;
        float y1 = (v1 - mean) * rstd * gg1 + bb1;
        float y2 = (v2 - mean) * rstd * gg2 + bb2;
        float y3 = (v3 - mean) * rstd * gg3 + bb3;
        uint2 o;
        o.x = (u32)f2bf(y0) | ((u32)f2bf(y1) << 16);
        o.y = (u32)f2bf(y2) | ((u32)f2bf(y3) << 16);
        ((uint2*)y)[t] = o;
    } else if (bx < PREP_LN + PREP_CVT) {
        // ---------------- param canonicalization ----------------
        int flag = detect_f32((const u16*)Q);
        int blk = bx - PREP_LN;
        const void* src;
        u16* dst;
        size_t srcoff;
        if (blk < 4096) {
            int w = blk >> 10;
            src = (w == 0) ? Wq : (w == 1) ? Wk : (w == 2) ? Wv : Wo;
            srcoff = (size_t)(blk & 1023) * 1024;
            dst = Wc + (size_t)w * 1024 * 1024 + srcoff;
        } else {
            int v = blk - 4096;
            src = (v == 0) ? vbq : (v == 1) ? vbk : (v == 2) ? vbv : (v == 3) ? vbo :
                  (v == 4) ? g0  : (v == 5) ? b0  : (v == 6) ? g1  : (v == 7) ? b1 :
                  (v == 8) ? g2  : b2;
            srcoff = 0;
            dst = Vc + (size_t)v * 1024;
        }
        u32 lo, hi;
        if (flag) {
            float4 x = ((const float4*)src)[srcoff / 4 + t];
            lo = (u32)f2bf(x.x) | ((u32)f2bf(x.y) << 16);
            hi = (u32)f2bf(x.z) | ((u32)f2bf(x.w) << 16);
        } else {
            uint2 x = ((const uint2*)src)[srcoff / 4 + t];
            lo = x.x; hi = x.y;
        }
        uint2 o; o.x = lo; o.y = hi;
        ((uint2*)dst)[t] = o;
    } else {
        // ---------------- cnt + zero Knc pad rows ----------------
        int b = bx - (PREP_LN + PREP_CVT);
        const int* m = pad_mask + (size_t)b * NSK;
        int s = 0;
#pragma unroll
        for (int i = 0; i < 8; ++i) s += (m[t * 8 + i] != 0) ? 1 : 0;
#pragma unroll
        for (int off = 32; off >= 1; off >>= 1) s += __shfl_xor(s, off);
        __shared__ int rs[4];
        int wave = t >> 6;
        if ((t & 63) == 0) rs[wave] = s;
        __syncthreads();
        int c = rs[0] + rs[1] + rs[2] + rs[3];
        if (t == 0) cnt[b] = c;
        int cPad = (c + 63) & ~63;
        int nel = (cPad - c) * ND;          // pad rows -> zero (finite GEMM out)
        u16* zp = Kn + ((size_t)b * NSK + c) * ND;
        for (int e = t * 8; e < nel; e += 256 * 8)
            *(uint4*)(zp + e) = (uint4){0, 0, 0, 0};
    }
}

// ---------------------------------------------------------------- fused 4x GEMM
// (round-6 known-good schedule) 256x256 tile, 8 waves (2M x 4N), BK=32,
// ring-4 LDS, ONE barrier per K-tile, counted vmcnt(8), drain 8->4->0.
// T2 both-sides swizzle; bijective XCD swizzle.
// NEW: Kn is COMPACT — z=1/z=2 row-tiles entirely beyond cPad early-exit.
// z=0: (Qn@Wq^T+bq)*log2e/32 -> Q1 ; z=1: Knc@Wk^T+bk -> K1 (compact)
// z=2: Knc@Wv^T+bv -> V1 (compact) ; z=3: relu(Qn@Wo^T+bo) -> R
__global__ __launch_bounds__(512, 2) void gemm4_kernel(
    const u16* __restrict__ Qn, const u16* __restrict__ Kn,
    const u16* __restrict__ Wc, const u16* __restrict__ Vc,
    const int* __restrict__ cnt,
    u16* __restrict__ Q1, u16* __restrict__ K1, u16* __restrict__ V1,
    u16* __restrict__ R)
{
    // XCD-aware remap of (bx,by,bz): lin increments x fastest (dispatch order)
    int lin = blockIdx.x + 16 * blockIdx.y + 64 * blockIdx.z;
    int u   = (lin & 7) * 32 + (lin >> 3);
    int bx  = u & 15;
    int by  = (u >> 4) & 3;
    int z   = u >> 6;

    if (z == 1 || z == 2) {
        int batch = bx >> 3;                        // 8 tiles per batch
        int cPad  = (cnt[batch] + 63) & ~63;
        if ((bx & 7) * 256 >= cPad) return;         // tile fully past keys
    }

    const u16* X    = (z == 0 || z == 3) ? Qn : Kn;
    const u16* W    = Wc + (size_t)z * 1024 * 1024;
    const u16* bias = Vc + (size_t)z * 1024;

    __shared__ u16 sm[4][2][256 * 32];   // 128 KiB: 4 slots x {A,B} x 16 KiB

    int tid  = threadIdx.x;
    int wave = tid >> 6, lane = tid & 63;
    int wm = wave >> 2, wn = wave & 3;          // 2M x 4N wave grid
    int quad = lane >> 4, l4 = lane & 15;
    int m0 = bx * 256;
    int n0 = by * 256;

    // staging: linear LDS dest (gload_lds requirement), pre-swizzled source
    int srow   = wave * 16 + (lane >> 2);                // rows 0..127 (inst0)
    int schunk = (lane & 3) ^ ((srow >> 1) & 3);         // inv-swizzle source
    const u16* gA = X + (size_t)(m0 + srow) * ND + schunk * 8;
    const u16* gB = W + (size_t)(n0 + srow) * ND + schunk * 8;

#define STAGE_A(t_) do { int s_ = (t_) & 3; \
    __builtin_amdgcn_global_load_lds((const AS1 u32*)(gA + (t_) * 32), \
        (AS3 u32*)(&sm[s_][0][wave * 512]), 16, 0, 0); \
    __builtin_amdgcn_global_load_lds((const AS1 u32*)(gA + (t_) * 32 + (size_t)128 * ND), \
        (AS3 u32*)(&sm[s_][0][4096 + wave * 512]), 16, 0, 0); \
} while (0)
#define STAGE_B(t_) do { int s_ = (t_) & 3; \
    __builtin_amdgcn_global_load_lds((const AS1 u32*)(gB + (t_) * 32), \
        (AS3 u32*)(&sm[s_][1][wave * 512]), 16, 0, 0); \
    __builtin_amdgcn_global_load_lds((const AS1 u32*)(gB + (t_) * 32 + (size_t)128 * ND), \
        (AS3 u32*)(&sm[s_][1][4096 + wave * 512]), 16, 0, 0); \
} while (0)

    // fragment read addressing; swizzled chunk is lane-constant:
    // row = 16*base + l4  ->  (row>>1)&3 == (l4>>1)&3
    int fch   = (quad ^ ((l4 >> 1) & 3)) * 8;
    int aoffb = (wm * 128 + l4) * 32 + fch;   // + mf*512
    int boffb = (wn * 64  + l4) * 32 + fch;   // + nf*512

    f32x4_t acc[8][4];
#pragma unroll
    for (int i = 0; i < 8; ++i)
#pragma unroll
        for (int j = 0; j < 4; ++j)
            acc[i][j] = (f32x4_t){0.f, 0.f, 0.f, 0.f};

    // prologue: 3 K-tiles in flight, validate tile 0 (8 loads may stay out)
    STAGE_A(0); STAGE_B(0);
    STAGE_A(1); STAGE_B(1);
    STAGE_A(2); STAGE_B(2);
    asm volatile("s_waitcnt vmcnt(8)" ::: "memory");
    __builtin_amdgcn_s_barrier();
    __builtin_amdgcn_sched_barrier(0);

    for (int t = 0; t < 32; ++t) {
        const u16* a = &sm[t & 3][0][0];
        const u16* b = &sm[t & 3][1][0];
        bf16x8_t bf[4], af[4], ah[4];

        // 12 ds_read_b128 (tile t) — compiler interleaves with MFMA via lgkmcnt
#pragma unroll
        for (int nf = 0; nf < 4; ++nf)
            bf[nf] = *(const bf16x8_t*)(b + boffb + nf * 512);
#pragma unroll
        for (int mf = 0; mf < 4; ++mf)
            af[mf] = *(const bf16x8_t*)(a + aoffb + mf * 512);
#pragma unroll
        for (int mf = 0; mf < 4; ++mf)
            ah[mf] = *(const bf16x8_t*)(a + aoffb + (mf + 4) * 512);

        // stage tile t+3 into slot (t-1)&3 (WAR-safe past last barrier)
        if (t < 29) { STAGE_A(t + 3); STAGE_B(t + 3); }

        __builtin_amdgcn_s_setprio(1);
#pragma unroll
        for (int mf = 0; mf < 4; ++mf)
#pragma unroll
            for (int nf = 0; nf < 4; ++nf)
                acc[mf][nf] = __builtin_amdgcn_mfma_f32_16x16x32_bf16(
                    af[mf], bf[nf], acc[mf][nf], 0, 0, 0);
#pragma unroll
        for (int mf = 0; mf < 4; ++mf)
#pragma unroll
            for (int nf = 0; nf < 4; ++nf)
                acc[mf + 4][nf] = __builtin_amdgcn_mfma_f32_16x16x32_bf16(
                    ah[mf], bf[nf], acc[mf + 4][nf], 0, 0, 0);
        __builtin_amdgcn_s_setprio(0);

        // K-tile boundary: validate tile t+1; keep tiles t+2,t+3 in flight
        if (t < 29)       asm volatile("s_waitcnt vmcnt(8)" ::: "memory");
        else if (t == 29) asm volatile("s_waitcnt vmcnt(4)" ::: "memory");
        else if (t == 30) asm volatile("s_waitcnt vmcnt(0)" ::: "memory");
        __builtin_amdgcn_s_barrier();
        __builtin_amdgcn_sched_barrier(0);
    }
#undef STAGE_A
#undef STAGE_B

    // epilogue: mf/r outer, nf inner -> line-complete store order
    u16* outp = (z == 0) ? Q1 : (z == 1) ? K1 : (z == 2) ? V1 : R;
    float bv_[4];
#pragma unroll
    for (int nf = 0; nf < 4; ++nf)
        bv_[nf] = bf2f(bias[n0 + wn * 64 + nf * 16 + l4]);
#pragma unroll
    for (int mf = 0; mf < 8; ++mf) {
#pragma unroll
        for (int r = 0; r < 4; ++r) {
            int m = m0 + wm * 128 + mf * 16 + quad * 4 + r;
#pragma unroll
            for (int nf = 0; nf < 4; ++nf) {
                int n = n0 + wn * 64 + nf * 16 + l4;
                float val = acc[mf][nf][r] + bv_[nf];
                if (z == 0) val *= 0.045105964f;   // (1/32) * log2(e)
                if (z == 3) val = fmaxf(val, 0.f);
                outp[(size_t)m * ND + n] = f2bf(val);
            }
        }
    }
}

// ---------------------------------------------------------------- V^T gather
// V1 is already COMPACT: Vct[b][h][d][j] = V1[b][j][h*64+d], fully coalesced,
// no index indirection. Rows [c, cPad) hold bias values — harmless (their
// P columns are exactly 0).
__global__ __launch_bounds__(256) void gather_vt_kernel(
    const u16* __restrict__ V1, const int* __restrict__ cnt,
    u16* __restrict__ Vct)
{
    int kb = blockIdx.x & 31;
    int h  = blockIdx.x >> 5;
    int b  = blockIdx.y;
    int c = cnt[b];
    int cPad = (c + 63) & ~63;
    if (kb * 64 >= cPad) return;
    __shared__ u16 sT[64 * 72];
    int tid = threadIdx.x;
    {
        int row = tid >> 3, seg = tid & 7;
        int j1 = kb * 64 + row, j2 = j1 + 32;
        uint4 v1 = *(const uint4*)(V1 + ((size_t)b * NSK + j1) * ND + h * NDH + seg * 8);
        uint4 v2 = *(const uint4*)(V1 + ((size_t)b * NSK + j2) * ND + h * NDH + seg * 8);
        *(uint4*)(sT + row * 72 + seg * 8) = v1;
        *(uint4*)(sT + (row + 32) * 72 + seg * 8) = v2;
    }
    __syncthreads();
    int d = tid >> 2, sg = tid & 3;
    u16 buf[16];
#pragma unroll
    for (int i = 0; i < 8; ++i) buf[i]     = sT[(sg * 8 + i) * 72 + d];
#pragma unroll
    for (int i = 0; i < 8; ++i) buf[8 + i] = sT[((sg + 4) * 8 + i) * 72 + d];
    u16* go = Vct + ((size_t)(b * NH + h) * NDH + d) * NSK + kb * 64;
    *(uint4*)(go + sg * 8)       = *(uint4*)buf;
    *(uint4*)(go + (sg + 4) * 8) = *(uint4*)(buf + 8);
}

// ---------------------------------------------------------------- flash attention
// (round-6 known-good) K1 is COMPACT -> staged directly (no Kc buffer).
// Tail keys [c, cPad) hold bias values; masked exactly by the -1e9 C-init.
// S^T = K.Q^T (x32 MFMA); PV x16 MFMA keeps P lane-local.
__global__ __launch_bounds__(256, 4) void attn_kernel(
    const u16* __restrict__ Q1, const u16* __restrict__ K1c,
    const u16* __restrict__ Vct, const int* __restrict__ cnt,
    u16* __restrict__ R)
{
    int q0 = blockIdx.x * 64;
    int h  = blockIdx.y;
    int b  = blockIdx.z;

    __shared__ u16 sK[2][64 * 64];
    __shared__ u16 sV[2][64 * 64];

    int tid  = threadIdx.x;
    int wave = tid >> 6, lane = tid & 63;
    int quad = lane >> 4, l4 = lane & 15;
    int lk = lane >> 3, ls = lane & 7;
    int gseg = ls ^ lk;

    int c  = cnt[b];
    int nt = (c + 63) >> 6;

    bf16x8_t qf[2];
    {
        const u16* qp = Q1 + (size_t)(b * NSQ + q0 + wave * 16 + l4) * ND + h * NDH;
        qf[0] = *(const bf16x8_t*)(qp + quad * 8);
        qf[1] = *(const bf16x8_t*)(qp + 32 + quad * 8);
    }

    const u16* kbase = K1c + (size_t)b * NSK * ND + h * NDH;
    const u16* vbase = Vct + (size_t)(b * NH + h) * NDH * NSK;

    const u16* gk0 = kbase + (size_t)(wave * 16 + lk) * ND + gseg * 8;
    const u16* gk1 = gk0 + (size_t)8 * ND;
    const u16* gv0 = vbase + (size_t)(wave * 16 + lk) * NSK + gseg * 8;
    const u16* gv1 = gv0 + (size_t)8 * NSK;

    // K-fragment (x32) swizzled offsets
    int fragOff[2];
#pragma unroll
    for (int kk = 0; kk < 2; ++kk)
        fragOff[kk] = l4 * 64 + (((kk * 4 + quad) ^ (l4 & 7)) * 8);

    // V-fragment (x16) swizzled offsets: keys 16*tm + 4*quad + j, row l4
    int v4off[4];
#pragma unroll
    for (int tm = 0; tm < 4; ++tm)
        v4off[tm] = l4 * 64 + (((2 * tm + (quad >> 1)) ^ (l4 & 7)) * 8)
                  + (quad & 1) * 4;

    float l_run = 0.f;
    f32x4_t acc_o[4];
#pragma unroll
    for (int T = 0; T < 4; ++T) acc_o[T] = (f32x4_t){0.f, 0.f, 0.f, 0.f};

    if (nt > 0) {
        __builtin_amdgcn_global_load_lds((const AS1 u32*)gk0,
            (AS3 u32*)(&sK[0][(wave * 16) * 64]), 16, 0, 0);
        __builtin_amdgcn_global_load_lds((const AS1 u32*)gk1,
            (AS3 u32*)(&sK[0][(wave * 16 + 8) * 64]), 16, 0, 0);
        __builtin_amdgcn_global_load_lds((const AS1 u32*)gv0,
            (AS3 u32*)(&sV[0][(wave * 16) * 64]), 16, 0, 0);
        __builtin_amdgcn_global_load_lds((const AS1 u32*)gv1,
            (AS3 u32*)(&sV[0][(wave * 16 + 8) * 64]), 16, 0, 0);
        gk0 += (size_t)64 * ND; gk1 += (size_t)64 * ND;
        gv0 += 64; gv1 += 64;

        for (int kb = 0; kb < nt; ++kb) {
            __syncthreads();

            if (kb + 1 < nt) {
                int bi = (kb + 1) & 1;
                __builtin_amdgcn_global_load_lds((const AS1 u32*)gk0,
                    (AS3 u32*)(&sK[bi][(wave * 16) * 64]), 16, 0, 0);
                __builtin_amdgcn_global_load_lds((const AS1 u32*)gk1,
                    (AS3 u32*)(&sK[bi][(wave * 16 + 8) * 64]), 16, 0, 0);
                __builtin_amdgcn_global_load_lds((const AS1 u32*)gv0,
                    (AS3 u32*)(&sV[bi][(wave * 16) * 64]), 16, 0, 0);
                __builtin_amdgcn_global_load_lds((const AS1 u32*)gv1,
                    (AS3 u32*)(&sV[bi][(wave * 16 + 8) * 64]), 16, 0, 0);
                gk0 += (size_t)64 * ND; gk1 += (size_t)64 * ND;
                gv0 += 64; gv1 += 64;
            }

            const u16* kt = sK[kb & 1];
            const u16* vt = sV[kb & 1];

            // C-init: 0 for valid keys; -1e9 on tail keys >= cnt
            f32x4_t accs[4];
            if (kb == nt - 1) {
#pragma unroll
                for (int tm = 0; tm < 4; ++tm) {
                    int key = kb * 64 + tm * 16 + quad * 4;
#pragma unroll
                    for (int r = 0; r < 4; ++r)
                        accs[tm][r] = (key + r < c) ? 0.f : -1e9f;
                }
            } else {
#pragma unroll
                for (int tm = 0; tm < 4; ++tm)
                    accs[tm] = (f32x4_t){0.f, 0.f, 0.f, 0.f};
            }
#pragma unroll
            for (int kk = 0; kk < 2; ++kk)
#pragma unroll
                for (int tm = 0; tm < 4; ++tm) {
                    bf16x8_t kf = *(const bf16x8_t*)(kt + tm * 1024 + fragOff[kk]);
                    accs[tm] = __builtin_amdgcn_mfma_f32_16x16x32_bf16(
                        kf, qf[kk], accs[tm], 0, 0, 0);
                }

            // softmax + PV fused: p = exp2(s) (Q pre-scaled by log2e/32);
            // P lane-local -> x16 MFMA directly, no cross-lane movement
            float lsum = 0.f;
#pragma unroll
            for (int tm = 0; tm < 4; ++tm) {
                float p0 = fexp2(accs[tm][0]);
                float p1 = fexp2(accs[tm][1]);
                float p2 = fexp2(accs[tm][2]);
                float p3 = fexp2(accs[tm][3]);
                lsum += (p0 + p1) + (p2 + p3);
                u32 lo = __builtin_amdgcn_perm(fbits(p1), fbits(p0), 0x07060302);
                u32 hi = __builtin_amdgcn_perm(fbits(p3), fbits(p2), 0x07060302);
                s16x4 pf = __builtin_bit_cast(s16x4, (u32x2_t){lo, hi});
#pragma unroll
                for (int T = 0; T < 4; ++T) {
                    s16x4 vf = *(const s16x4*)(vt + T * 1024 + v4off[tm]);
                    acc_o[T] = mfma16(vf, pf, acc_o[T]);
                }
            }
            lsum += __shfl_xor(lsum, 16);
            lsum += __shfl_xor(lsum, 32);
            l_run += lsum;
        }
    }

    // epilogue: O[q][d] = acc_o / l ; R += O1 (uint2 RMW)
    float inv = l_run > 0.f ? 1.f / l_run : 0.f;
    u16* rp = R + (size_t)(b * NSQ + q0 + wave * 16 + l4) * ND + h * NDH;
#pragma unroll
    for (int T = 0; T < 4; ++T) {
        u16* p = rp + T * 16 + quad * 4;
        uint2 o2 = *(const uint2*)p;
        float e0 = acc_o[T][0] * inv + bf2f(o2.x & 0xffff);
        float e1 = acc_o[T][1] * inv + bf2f(o2.x >> 16);
        float e2 = acc_o[T][2] * inv + bf2f(o2.y & 0xffff);
        float e3 = acc_o[T][3] * inv + bf2f(o2.y >> 16);
        uint2 on;
        on.x = (u32)f2bf(e0) | ((u32)f2bf(e1) << 16);
        on.y = (u32)f2bf(e2) | ((u32)f2bf(e3) << 16);
        *(uint2*)p = on;
    }
}

// ---------------------------------------------------------------- final LN
__global__ __launch_bounds__(256) void ln_out_kernel(
    const void* __restrict__ Q, const u16* __restrict__ R,
    const u16* __restrict__ Vc, void* __restrict__ out)
{
    int row = blockIdx.x;
    size_t roff = (size_t)row * ND;
    int t = threadIdx.x;
    int f = detect_f32((const u16*)Q);
    float v0, v1, v2, v3;
    uint2 ur = ((const uint2*)(R + roff))[t];
    if (f) {
        float4 xq = ((const float4*)Q)[roff / 4 + t];
        v0 = xq.x; v1 = xq.y; v2 = xq.z; v3 = xq.w;
    } else {
        uint2 uq = ((const uint2*)Q)[roff / 4 + t];
        v0 = bf2f(uq.x & 0xffff); v1 = bf2f(uq.x >> 16);
        v2 = bf2f(uq.y & 0xffff); v3 = bf2f(uq.y >> 16);
    }
    v0 += bf2f(ur.x & 0xffff); v1 += bf2f(ur.x >> 16);
    v2 += bf2f(ur.y & 0xffff); v3 += bf2f(ur.y >> 16);
    float s1 = v0 + v1 + v2 + v3;
    float s2 = v0*v0 + v1*v1 + v2*v2 + v3*v3;
#pragma unroll
    for (int off = 32; off >= 1; off >>= 1) {
        s1 += __shfl_xor(s1, off);
        s2 += __shfl_xor(s2, off);
    }
    __shared__ float r1[4], r2[4];
    int wave = t >> 6;
    if ((t & 63) == 0) { r1[wave] = s1; r2[wave] = s2; }
    __syncthreads();
    float t1 = r1[0] + r1[1] + r1[2] + r1[3];
    float t2 = r2[0] + r2[1] + r2[2] + r2[3];
    float mean = t1 * (1.0f / ND);
    float var  = t2 * (1.0f / ND) - mean * mean;
    float rstd = rsqrtf(var + 1e-5f);
    const u16* g  = Vc + 8 * 1024;
    const u16* bb = Vc + 9 * 1024;
    uint2 ug = ((const uint2*)g)[t];
    uint2 ub = ((const uint2*)bb)[t];
    float y0 = (v0 - mean) * rstd * bf2f(ug.x & 0xffff) + bf2f(ub.x & 0xffff);
    float y1 = (v1 - mean) * rstd * bf2f(ug.x >> 16)    + bf2f(ub.x >> 16);
    float y2 = (v2 - mean) * rstd * bf2f(ug.y & 0xffff) + bf2f(ub.y & 0xffff);
    float y3 = (v3 - mean) * rstd * bf2f(ug.y >> 16)    + bf2f(ub.y >> 16);
    if (f) {
        float4 o; o.x = y0; o.y = y1; o.z = y2; o.w = y3;
        ((float4*)out)[roff / 4 + t] = o;
    } else {
        uint2 o;
        o.x = (u32)f2bf(y0) | ((u32)f2bf(y1) << 16);
        o.y = (u32)f2bf(y2) | ((u32)f2bf(y3) << 16);
        ((uint2*)out)[roff / 4 + t] = o;
    }
}

// ---------------------------------------------------------------- launch
extern "C" void kernel_launch(void* const* d_in, const int* in_sizes, int n_in,
                              void* d_out, int out_size, void* d_ws, size_t ws_size,
                              hipStream_t stream) {
    const void* Q        = d_in[0];
    const void* K        = d_in[1];
    const int* pad_mask  = (const int*)d_in[2];

    const size_t NEL = (size_t)NB * NSQ * ND;   // 4,194,304
    int* flag = (int*)d_ws;                      // [0] (unused; layout keep)
    int* cnt  = flag + 1;                        // [1..3)
    u16* base = (u16*)(flag + 4168);             // 16-byte aligned
    u16* Qn  = base;
    u16* Kn  = Qn + NEL;                         // COMPACT after prep
    u16* Q1  = Kn + NEL;
    u16* K1  = Q1 + NEL;                         // COMPACT after gemm4
    u16* V1  = K1 + NEL;                         // COMPACT after gemm4
    u16* R   = V1 + NEL;
    u16* Wc  = R + NEL;
    u16* Vc  = Wc + (size_t)4 * 1024 * 1024;
    u16* Vct = Kn;                               // aliases Kn (dead after gemm4)

    prep_kernel<<<dim3(PREP_LN + PREP_CVT + NB), dim3(256), 0, stream>>>(
        Q, K, pad_mask,
        d_in[3], d_in[4], d_in[5], d_in[6],
        d_in[7], d_in[8], d_in[9], d_in[10],
        d_in[11], d_in[12], d_in[13], d_in[14], d_in[15], d_in[16],
        Wc, Vc, cnt, Qn, Kn);

    gemm4_kernel<<<dim3(16, 4, 4), dim3(512), 0, stream>>>(
        Qn, Kn, Wc, Vc, cnt, Q1, K1, V1, R);

    gather_vt_kernel<<<dim3(32 * NH, NB), dim3(256), 0, stream>>>(
        V1, cnt, Vct);

    attn_kernel<<<dim3(NSQ / 64, NH, NB), dim3(256), 0, stream>>>(
        Q1, K1, Vct, cnt, R);

    ln_out_kernel<<<dim3(NB * NSQ), dim3(256), 0, stream>>>(
        Q, R, Vc, d_out);
}

// Round 12
// 206.916 us; speedup vs baseline: 1.8415x; 1.0501x over previous
//
#include <hip/hip_runtime.h>
#include <stdint.h>

#define NB 2
#define NSQ 2048
#define NSK 2048
#define ND 1024
#define NH 16
#define NDH 64

typedef unsigned short u16;
typedef unsigned int u32;
typedef __bf16 bf16x8_t __attribute__((ext_vector_type(8)));
typedef float f32x4_t __attribute__((ext_vector_type(4)));
typedef u32 u32x4_t __attribute__((ext_vector_type(4)));
typedef short s16x4 __attribute__((ext_vector_type(4)));
typedef u32 u32x2_t __attribute__((ext_vector_type(2)));

#define AS1 __attribute__((address_space(1)))
#define AS3 __attribute__((address_space(3)))

__device__ __forceinline__ float bf2f(u16 u) {
    union { float f; u32 i; } v; v.i = ((u32)u) << 16; return v.f;
}
__device__ __forceinline__ u16 f2bf(float x) {
    union { float f; u32 i; } v; v.f = x;
    u32 r = v.i + 0x7fffu + ((v.i >> 16) & 1u);
    return (u16)(r >> 16);
}
__device__ __forceinline__ u32 fbits(float x) {
    union { float f; u32 i; } v; v.f = x; return v.i;
}
__device__ __forceinline__ float fexp2(float x) {
#if __has_builtin(__builtin_amdgcn_exp2f)
    return __builtin_amdgcn_exp2f(x);   // raw v_exp_f32 (base-2)
#else
    return exp2f(x);
#endif
}
// 16x16x16 bf16 MFMA: A/B = 4 bf16 per lane (k = quad*4 + j) — matches the
// QK^T C-fragment key grouping, so P feeds PV with NO cross-lane movement.
__device__ __forceinline__ f32x4_t mfma16(s16x4 a, s16x4 b, f32x4_t c) {
#if __has_builtin(__builtin_amdgcn_mfma_f32_16x16x16bf16_1k)
    return __builtin_amdgcn_mfma_f32_16x16x16bf16_1k(a, b, c, 0, 0, 0);
#else
    asm("v_mfma_f32_16x16x16_bf16 %0, %1, %2, %0" : "+v"(c) : "v"(a), "v"(b));
    return c;
#endif
}
// wave-uniform dtype detect: all lanes read the same first 512B of Q (L2-hot);
// f32 inputs -> low u16s are mantissa bits, virtually surely "exp">=0x8D.
__device__ __forceinline__ int detect_f32(const u16* __restrict__ Q) {
    uint2 x = ((const uint2*)Q)[threadIdx.x & 63];
    u16 a0 = x.x & 0xffff, a1 = x.x >> 16, a2 = x.y & 0xffff, a3 = x.y >> 16;
    bool big = (((a0 >> 7) & 0xff) >= 0x8D) || (((a1 >> 7) & 0xff) >= 0x8D) ||
               (((a2 >> 7) & 0xff) >= 0x8D) || (((a3 >> 7) & 0xff) >= 0x8D);
    return __any(big);   // 1 = f32 inputs, 0 = bf16 inputs (wave-uniform)
}

// ---------------------------------------------------------------- fused prep
// (round-6 verbatim) Block roles by blockIdx.x:
//   [0, 8192)            : input LN  (row = bx); gamma/beta read RAW
//   [8192, 8192+4106)    : param canonicalization (weights + vectors -> bf16)
//   [12298, 12300)       : key index compaction (idx + cnt per batch)
#define PREP_LN   (2 * NB * NSQ)          // 8192
#define PREP_CVT  4106
__global__ __launch_bounds__(256) void prep_kernel(
    const void* __restrict__ Q, const void* __restrict__ K,
    const int* __restrict__ pad_mask,
    const void* __restrict__ Wq, const void* __restrict__ Wk,
    const void* __restrict__ Wv, const void* __restrict__ Wo,
    const void* __restrict__ vbq, const void* __restrict__ vbk,
    const void* __restrict__ vbv, const void* __restrict__ vbo,
    const void* __restrict__ g0, const void* __restrict__ b0,
    const void* __restrict__ g1, const void* __restrict__ b1,
    const void* __restrict__ g2, const void* __restrict__ b2,
    u16* __restrict__ Wc, u16* __restrict__ Vc,
    int* __restrict__ idx, int* __restrict__ cnt,
    u16* __restrict__ Qn, u16* __restrict__ Kn)
{
    int bx = blockIdx.x;
    int t  = threadIdx.x;

    if (bx < PREP_LN) {
        // ---------------- input LN ----------------
        int flag = detect_f32((const u16*)Q);
        int row = bx;
        const void* x; const void *gv, *bv; u16* y;
        size_t roff;
        if (row < NB * NSQ) {
            x = Q; roff = (size_t)row * ND;
            gv = g0; bv = b0;
            y = Qn + roff;
        } else {
            int r2 = row - NB * NSQ;
            x = K; roff = (size_t)r2 * ND;
            gv = g1; bv = b1;
            y = Kn + roff;
        }
        float v0, v1, v2, v3, gg0, gg1, gg2, gg3, bb0, bb1, bb2, bb3;
        if (flag) {
            float4 xv = ((const float4*)x)[roff / 4 + t];
            v0 = xv.x; v1 = xv.y; v2 = xv.z; v3 = xv.w;
            float4 G = ((const float4*)gv)[t];
            float4 Bv = ((const float4*)bv)[t];
            gg0 = G.x; gg1 = G.y; gg2 = G.z; gg3 = G.w;
            bb0 = Bv.x; bb1 = Bv.y; bb2 = Bv.z; bb3 = Bv.w;
        } else {
            uint2 ux = ((const uint2*)x)[roff / 4 + t];
            v0 = bf2f(ux.x & 0xffff); v1 = bf2f(ux.x >> 16);
            v2 = bf2f(ux.y & 0xffff); v3 = bf2f(ux.y >> 16);
            uint2 G = ((const uint2*)gv)[t];
            uint2 Bv = ((const uint2*)bv)[t];
            gg0 = bf2f(G.x & 0xffff); gg1 = bf2f(G.x >> 16);
            gg2 = bf2f(G.y & 0xffff); gg3 = bf2f(G.y >> 16);
            bb0 = bf2f(Bv.x & 0xffff); bb1 = bf2f(Bv.x >> 16);
            bb2 = bf2f(Bv.y & 0xffff); bb3 = bf2f(Bv.y >> 16);
        }
        float s1 = v0 + v1 + v2 + v3;
        float s2 = v0*v0 + v1*v1 + v2*v2 + v3*v3;
#pragma unroll
        for (int off = 32; off >= 1; off >>= 1) {
            s1 += __shfl_xor(s1, off);
            s2 += __shfl_xor(s2, off);
        }
        __shared__ float r1[4], r2[4];
        int wave = t >> 6;
        if ((t & 63) == 0) { r1[wave] = s1; r2[wave] = s2; }
        __syncthreads();
        float t1 = r1[0] + r1[1] + r1[2] + r1[3];
        float t2 = r2[0] + r2[1] + r2[2] + r2[3];
        float mean = t1 * (1.0f / ND);
        float var  = t2 * (1.0f / ND) - mean * mean;
        float rstd = rsqrtf(var + 1e-5f);
        float y0 = (v0 - mean) * rstd * gg0 + bb0;
        float y1 = (v1 - mean) * rstd * gg1 + bb1;
        float y2 = (v2 - mean) * rstd * gg2 + bb2;
        float y3 = (v3 - mean) * rstd * gg3 + bb3;
        uint2 o;
        o.x = (u32)f2bf(y0) | ((u32)f2bf(y1) << 16);
        o.y = (u32)f2bf(y2) | ((u32)f2bf(y3) << 16);
        ((uint2*)y)[t] = o;
    } else if (bx < PREP_LN + PREP_CVT) {
        // ---------------- param canonicalization ----------------
        int flag = detect_f32((const u16*)Q);
        int blk = bx - PREP_LN;
        const void* src;
        u16* dst;
        size_t srcoff;
        if (blk < 4096) {
            int w = blk >> 10;
            src = (w == 0) ? Wq : (w == 1) ? Wk : (w == 2) ? Wv : Wo;
            srcoff = (size_t)(blk & 1023) * 1024;
            dst = Wc + (size_t)w * 1024 * 1024 + srcoff;
        } else {
            int v = blk - 4096;
            src = (v == 0) ? vbq : (v == 1) ? vbk : (v == 2) ? vbv : (v == 3) ? vbo :
                  (v == 4) ? g0  : (v == 5) ? b0  : (v == 6) ? g1  : (v == 7) ? b1 :
                  (v == 8) ? g2  : b2;
            srcoff = 0;
            dst = Vc + (size_t)v * 1024;
        }
        u32 lo, hi;
        if (flag) {
            float4 x = ((const float4*)src)[srcoff / 4 + t];
            lo = (u32)f2bf(x.x) | ((u32)f2bf(x.y) << 16);
            hi = (u32)f2bf(x.z) | ((u32)f2bf(x.w) << 16);
        } else {
            uint2 x = ((const uint2*)src)[srcoff / 4 + t];
            lo = x.x; hi = x.y;
        }
        uint2 o; o.x = lo; o.y = hi;
        ((uint2*)dst)[t] = o;
    } else {
        // ---------------- key index compaction ----------------
        int b = bx - (PREP_LN + PREP_CVT);
        const int* m = pad_mask + b * NSK;
        int loc[8]; int s = 0;
#pragma unroll
        for (int i = 0; i < 8; ++i) { loc[i] = (m[t * 8 + i] != 0); s += loc[i]; }
        __shared__ int ps[256];
        ps[t] = s;
        __syncthreads();
        for (int off = 1; off < 256; off <<= 1) {
            int v = (t >= off) ? ps[t - off] : 0;
            __syncthreads();
            ps[t] += v;
            __syncthreads();
        }
        int run = ps[t] - s;   // exclusive prefix
#pragma unroll
        for (int i = 0; i < 8; ++i)
            if (loc[i]) idx[b * NSK + run++] = t * 8 + i;
        if (t == 255) cnt[b] = ps[255];
    }
}

// ---------------------------------------------------------------- fused 4x GEMM
// (round-6 schedule) 256x256 tile, 8 waves (2M x 4N), BK=32, ring-4 LDS,
// ONE barrier per K-tile, counted vmcnt(8), drain 8->4->0. T2 both-sides
// swizzle; bijective XCD swizzle.
// COMPACTION rides the A-addressing for z=1/z=2: staged row = idx[j]
// (per-lane source; idx loads at PROLOGUE only — row is loop-invariant).
// Tail rows j>=c clamp to row 0 (finite; masked by attn's -1e9 C-init).
// Tiles fully past cPad early-exit. z=2 epilogue writes TRANSPOSED directly
// to Vct (row = batch*1024 + n, col = j) — kills the gather kernel.
// z=0: (Qn@Wq^T+bq)*log2e/32 -> Q1 ; z=1: Kn[idx]@Wk^T+bk -> K1 (compact)
// z=2: Kn[idx]@Wv^T+bv -> Vct (transposed) ; z=3: relu(Qn@Wo^T+bo) -> R
__global__ __launch_bounds__(512, 2) void gemm4_kernel(
    const u16* __restrict__ Qn, const u16* __restrict__ Kn,
    const u16* __restrict__ Wc, const u16* __restrict__ Vc,
    const int* __restrict__ cnt, const int* __restrict__ idx,
    u16* __restrict__ Q1, u16* __restrict__ K1, u16* __restrict__ Vct,
    u16* __restrict__ R)
{
    // XCD-aware remap of (bx,by,bz): lin increments x fastest (dispatch order)
    int lin = blockIdx.x + 16 * blockIdx.y + 64 * blockIdx.z;
    int u   = (lin & 7) * 32 + (lin >> 3);
    int bx  = u & 15;
    int by  = (u >> 4) & 3;
    int z   = u >> 6;

    int kv = (z == 1 || z == 2);
    int batch = bx >> 3;
    int c2 = 0;
    if (kv) {
        c2 = cnt[batch];
        int cPad = (c2 + 63) & ~63;
        if ((bx & 7) * 256 >= cPad) return;         // tile fully past keys
    }

    const u16* X    = (z == 0 || z == 3) ? Qn : Kn;
    const u16* W    = Wc + (size_t)z * 1024 * 1024;
    const u16* bias = Vc + (size_t)z * 1024;

    __shared__ u16 sm[4][2][256 * 32];   // 128 KiB: 4 slots x {A,B} x 16 KiB

    int tid  = threadIdx.x;
    int wave = tid >> 6, lane = tid & 63;
    int wm = wave >> 2, wn = wave & 3;          // 2M x 4N wave grid
    int quad = lane >> 4, l4 = lane & 15;
    int m0 = bx * 256;
    int n0 = by * 256;

    // staging: linear LDS dest (gload_lds requirement), pre-swizzled source.
    // Swizzle is keyed to the LDS DEST row -> valid for remapped source rows.
    int srow   = wave * 16 + (lane >> 2);                // dest rows (inst0)
    int schunk = (lane & 3) ^ ((srow >> 1) & 3);         // inv-swizzle source
    const u16 *gA0, *gA1;
    if (kv) {
        int jg0 = (bx & 7) * 256 + srow;                 // compacted key index
        int jg1 = jg0 + 128;
        int ar0 = (jg0 < c2) ? idx[batch * NSK + jg0] : 0;
        int ar1 = (jg1 < c2) ? idx[batch * NSK + jg1] : 0;
        gA0 = Kn + ((size_t)batch * NSK + ar0) * ND + schunk * 8;
        gA1 = Kn + ((size_t)batch * NSK + ar1) * ND + schunk * 8;
    } else {
        gA0 = X + (size_t)(m0 + srow) * ND + schunk * 8;
        gA1 = gA0 + (size_t)128 * ND;
    }
    const u16* gB = W + (size_t)(n0 + srow) * ND + schunk * 8;

#define STAGE_A(t_) do { int s_ = (t_) & 3; \
    __builtin_amdgcn_global_load_lds((const AS1 u32*)(gA0 + (t_) * 32), \
        (AS3 u32*)(&sm[s_][0][wave * 512]), 16, 0, 0); \
    __builtin_amdgcn_global_load_lds((const AS1 u32*)(gA1 + (t_) * 32), \
        (AS3 u32*)(&sm[s_][0][4096 + wave * 512]), 16, 0, 0); \
} while (0)
#define STAGE_B(t_) do { int s_ = (t_) & 3; \
    __builtin_amdgcn_global_load_lds((const AS1 u32*)(gB + (t_) * 32), \
        (AS3 u32*)(&sm[s_][1][wave * 512]), 16, 0, 0); \
    __builtin_amdgcn_global_load_lds((const AS1 u32*)(gB + (t_) * 32 + (size_t)128 * ND), \
        (AS3 u32*)(&sm[s_][1][4096 + wave * 512]), 16, 0, 0); \
} while (0)

    // fragment read addressing; swizzled chunk is lane-constant:
    // row = 16*base + l4  ->  (row>>1)&3 == (l4>>1)&3
    int fch   = (quad ^ ((l4 >> 1) & 3)) * 8;
    int aoffb = (wm * 128 + l4) * 32 + fch;   // + mf*512
    int boffb = (wn * 64  + l4) * 32 + fch;   // + nf*512

    f32x4_t acc[8][4];
#pragma unroll
    for (int i = 0; i < 8; ++i)
#pragma unroll
        for (int j = 0; j < 4; ++j)
            acc[i][j] = (f32x4_t){0.f, 0.f, 0.f, 0.f};

    // prologue: 3 K-tiles in flight, validate tile 0 (8 loads may stay out)
    STAGE_A(0); STAGE_B(0);
    STAGE_A(1); STAGE_B(1);
    STAGE_A(2); STAGE_B(2);
    asm volatile("s_waitcnt vmcnt(8)" ::: "memory");
    __builtin_amdgcn_s_barrier();
    __builtin_amdgcn_sched_barrier(0);

    for (int t = 0; t < 32; ++t) {
        const u16* a = &sm[t & 3][0][0];
        const u16* b = &sm[t & 3][1][0];
        bf16x8_t bf[4], af[4], ah[4];

        // 12 ds_read_b128 (tile t) — compiler interleaves with MFMA via lgkmcnt
#pragma unroll
        for (int nf = 0; nf < 4; ++nf)
            bf[nf] = *(const bf16x8_t*)(b + boffb + nf * 512);
#pragma unroll
        for (int mf = 0; mf < 4; ++mf)
            af[mf] = *(const bf16x8_t*)(a + aoffb + mf * 512);
#pragma unroll
        for (int mf = 0; mf < 4; ++mf)
            ah[mf] = *(const bf16x8_t*)(a + aoffb + (mf + 4) * 512);

        // stage tile t+3 into slot (t-1)&3 (WAR-safe past last barrier)
        if (t < 29) { STAGE_A(t + 3); STAGE_B(t + 3); }

        __builtin_amdgcn_s_setprio(1);
#pragma unroll
        for (int mf = 0; mf < 4; ++mf)
#pragma unroll
            for (int nf = 0; nf < 4; ++nf)
                acc[mf][nf] = __builtin_amdgcn_mfma_f32_16x16x32_bf16(
                    af[mf], bf[nf], acc[mf][nf], 0, 0, 0);
#pragma unroll
        for (int mf = 0; mf < 4; ++mf)
#pragma unroll
            for (int nf = 0; nf < 4; ++nf)
                acc[mf + 4][nf] = __builtin_amdgcn_mfma_f32_16x16x32_bf16(
                    ah[mf], bf[nf], acc[mf + 4][nf], 0, 0, 0);
        __builtin_amdgcn_s_setprio(0);

        // K-tile boundary: validate tile t+1; keep tiles t+2,t+3 in flight
        if (t < 29)       asm volatile("s_waitcnt vmcnt(8)" ::: "memory");
        else if (t == 29) asm volatile("s_waitcnt vmcnt(4)" ::: "memory");
        else if (t == 30) asm volatile("s_waitcnt vmcnt(0)" ::: "memory");
        __builtin_amdgcn_s_barrier();
        __builtin_amdgcn_sched_barrier(0);
    }
#undef STAGE_A
#undef STAGE_B

    float bv_[4];
#pragma unroll
    for (int nf = 0; nf < 4; ++nf)
        bv_[nf] = bf2f(bias[n0 + wn * 64 + nf * 16 + l4]);

    if (z == 2) {
        // transposed epilogue: Vct[(batch*1024 + n) * NSK + j]  (h*64+d == n)
        int jb = (bx & 7) * 256 + wm * 128;
#pragma unroll
        for (int nf = 0; nf < 4; ++nf) {
            int n = n0 + wn * 64 + nf * 16 + l4;
            float bvv = bv_[nf];
            u16* rowp = Vct + ((size_t)batch * 1024 + n) * NSK;
#pragma unroll
            for (int mf = 0; mf < 8; ++mf) {
                int j = jb + mf * 16 + quad * 4;
                uint2 o;
                o.x = (u32)f2bf(acc[mf][nf][0] + bvv)
                    | ((u32)f2bf(acc[mf][nf][1] + bvv) << 16);
                o.y = (u32)f2bf(acc[mf][nf][2] + bvv)
                    | ((u32)f2bf(acc[mf][nf][3] + bvv) << 16);
                *(uint2*)(rowp + j) = o;
            }
        }
        return;
    }

    // epilogue (z=0,1,3): mf/r outer, nf inner -> line-complete store order
    u16* outp = (z == 0) ? Q1 : (z == 1) ? K1 : R;
#pragma unroll
    for (int mf = 0; mf < 8; ++mf) {
#pragma unroll
        for (int r = 0; r < 4; ++r) {
            int m = m0 + wm * 128 + mf * 16 + quad * 4 + r;
#pragma unroll
            for (int nf = 0; nf < 4; ++nf) {
                int n = n0 + wn * 64 + nf * 16 + l4;
                float val = acc[mf][nf][r] + bv_[nf];
                if (z == 0) val *= 0.045105964f;   // (1/32) * log2(e)
                if (z == 3) val = fmaxf(val, 0.f);
                outp[(size_t)m * ND + n] = f2bf(val);
            }
        }
    }
}

// ---------------------------------------------------------------- flash attention
// (round-6 known-good) K1 compact, Vct transposed — both produced by gemm4.
// Tail keys [c, cPad) hold finite garbage; masked exactly by the -1e9 C-init.
// S^T = K.Q^T (x32 MFMA); PV x16 MFMA keeps P lane-local.
__global__ __launch_bounds__(256, 4) void attn_kernel(
    const u16* __restrict__ Q1, const u16* __restrict__ K1c,
    const u16* __restrict__ Vct, const int* __restrict__ cnt,
    u16* __restrict__ R)
{
    int q0 = blockIdx.x * 64;
    int h  = blockIdx.y;
    int b  = blockIdx.z;

    __shared__ u16 sK[2][64 * 64];
    __shared__ u16 sV[2][64 * 64];

    int tid  = threadIdx.x;
    int wave = tid >> 6, lane = tid & 63;
    int quad = lane >> 4, l4 = lane & 15;
    int lk = lane >> 3, ls = lane & 7;
    int gseg = ls ^ lk;

    int c  = cnt[b];
    int nt = (c + 63) >> 6;

    bf16x8_t qf[2];
    {
        const u16* qp = Q1 + (size_t)(b * NSQ + q0 + wave * 16 + l4) * ND + h * NDH;
        qf[0] = *(const bf16x8_t*)(qp + quad * 8);
        qf[1] = *(const bf16x8_t*)(qp + 32 + quad * 8);
    }

    const u16* kbase = K1c + (size_t)b * NSK * ND + h * NDH;
    const u16* vbase = Vct + (size_t)(b * NH + h) * NDH * NSK;

    const u16* gk0 = kbase + (size_t)(wave * 16 + lk) * ND + gseg * 8;
    const u16* gk1 = gk0 + (size_t)8 * ND;
    const u16* gv0 = vbase + (size_t)(wave * 16 + lk) * NSK + gseg * 8;
    const u16* gv1 = gv0 + (size_t)8 * NSK;

    // K-fragment (x32) swizzled offsets
    int fragOff[2];
#pragma unroll
    for (int kk = 0; kk < 2; ++kk)
        fragOff[kk] = l4 * 64 + (((kk * 4 + quad) ^ (l4 & 7)) * 8);

    // V-fragment (x16) swizzled offsets: keys 16*tm + 4*quad + j, row l4
    int v4off[4];
#pragma unroll
    for (int tm = 0; tm < 4; ++tm)
        v4off[tm] = l4 * 64 + (((2 * tm + (quad >> 1)) ^ (l4 & 7)) * 8)
                  + (quad & 1) * 4;

    float l_run = 0.f;
    f32x4_t acc_o[4];
#pragma unroll
    for (int T = 0; T < 4; ++T) acc_o[T] = (f32x4_t){0.f, 0.f, 0.f, 0.f};

    if (nt > 0) {
        __builtin_amdgcn_global_load_lds((const AS1 u32*)gk0,
            (AS3 u32*)(&sK[0][(wave * 16) * 64]), 16, 0, 0);
        __builtin_amdgcn_global_load_lds((const AS1 u32*)gk1,
            (AS3 u32*)(&sK[0][(wave * 16 + 8) * 64]), 16, 0, 0);
        __builtin_amdgcn_global_load_lds((const AS1 u32*)gv0,
            (AS3 u32*)(&sV[0][(wave * 16) * 64]), 16, 0, 0);
        __builtin_amdgcn_global_load_lds((const AS1 u32*)gv1,
            (AS3 u32*)(&sV[0][(wave * 16 + 8) * 64]), 16, 0, 0);
        gk0 += (size_t)64 * ND; gk1 += (size_t)64 * ND;
        gv0 += 64; gv1 += 64;

        for (int kb = 0; kb < nt; ++kb) {
            __syncthreads();

            if (kb + 1 < nt) {
                int bi = (kb + 1) & 1;
                __builtin_amdgcn_global_load_lds((const AS1 u32*)gk0,
                    (AS3 u32*)(&sK[bi][(wave * 16) * 64]), 16, 0, 0);
                __builtin_amdgcn_global_load_lds((const AS1 u32*)gk1,
                    (AS3 u32*)(&sK[bi][(wave * 16 + 8) * 64]), 16, 0, 0);
                __builtin_amdgcn_global_load_lds((const AS1 u32*)gv0,
                    (AS3 u32*)(&sV[bi][(wave * 16) * 64]), 16, 0, 0);
                __builtin_amdgcn_global_load_lds((const AS1 u32*)gv1,
                    (AS3 u32*)(&sV[bi][(wave * 16 + 8) * 64]), 16, 0, 0);
                gk0 += (size_t)64 * ND; gk1 += (size_t)64 * ND;
                gv0 += 64; gv1 += 64;
            }

            const u16* kt = sK[kb & 1];
            const u16* vt = sV[kb & 1];

            // C-init: 0 for valid keys; -1e9 on tail keys >= cnt
            f32x4_t accs[4];
            if (kb == nt - 1) {
#pragma unroll
                for (int tm = 0; tm < 4; ++tm) {
                    int key = kb * 64 + tm * 16 + quad * 4;
#pragma unroll
                    for (int r = 0; r < 4; ++r)
                        accs[tm][r] = (key + r < c) ? 0.f : -1e9f;
                }
            } else {
#pragma unroll
                for (int tm = 0; tm < 4; ++tm)
                    accs[tm] = (f32x4_t){0.f, 0.f, 0.f, 0.f};
            }
#pragma unroll
            for (int kk = 0; kk < 2; ++kk)
#pragma unroll
                for (int tm = 0; tm < 4; ++tm) {
                    bf16x8_t kf = *(const bf16x8_t*)(kt + tm * 1024 + fragOff[kk]);
                    accs[tm] = __builtin_amdgcn_mfma_f32_16x16x32_bf16(
                        kf, qf[kk], accs[tm], 0, 0, 0);
                }

            // softmax + PV fused: p = exp2(s) (Q pre-scaled by log2e/32);
            // P lane-local -> x16 MFMA directly, no cross-lane movement
            float lsum = 0.f;
#pragma unroll
            for (int tm = 0; tm < 4; ++tm) {
                float p0 = fexp2(accs[tm][0]);
                float p1 = fexp2(accs[tm][1]);
                float p2 = fexp2(accs[tm][2]);
                float p3 = fexp2(accs[tm][3]);
                lsum += (p0 + p1) + (p2 + p3);
                u32 lo = __builtin_amdgcn_perm(fbits(p1), fbits(p0), 0x07060302);
                u32 hi = __builtin_amdgcn_perm(fbits(p3), fbits(p2), 0x07060302);
                s16x4 pf = __builtin_bit_cast(s16x4, (u32x2_t){lo, hi});
#pragma unroll
                for (int T = 0; T < 4; ++T) {
                    s16x4 vf = *(const s16x4*)(vt + T * 1024 + v4off[tm]);
                    acc_o[T] = mfma16(vf, pf, acc_o[T]);
                }
            }
            lsum += __shfl_xor(lsum, 16);
            lsum += __shfl_xor(lsum, 32);
            l_run += lsum;
        }
    }

    // epilogue: O[q][d] = acc_o / l ; R += O1 (uint2 RMW)
    float inv = l_run > 0.f ? 1.f / l_run : 0.f;
    u16* rp = R + (size_t)(b * NSQ + q0 + wave * 16 + l4) * ND + h * NDH;
#pragma unroll
    for (int T = 0; T < 4; ++T) {
        u16* p = rp + T * 16 + quad * 4;
        uint2 o2 = *(const uint2*)p;
        float e0 = acc_o[T][0] * inv + bf2f(o2.x & 0xffff);
        float e1 = acc_o[T][1] * inv + bf2f(o2.x >> 16);
        float e2 = acc_o[T][2] * inv + bf2f(o2.y & 0xffff);
        float e3 = acc_o[T][3] * inv + bf2f(o2.y >> 16);
        uint2 on;
        on.x = (u32)f2bf(e0) | ((u32)f2bf(e1) << 16);
        on.y = (u32)f2bf(e2) | ((u32)f2bf(e3) << 16);
        *(uint2*)p = on;
    }
}

// ---------------------------------------------------------------- final LN
__global__ __launch_bounds__(256) void ln_out_kernel(
    const void* __restrict__ Q, const u16* __restrict__ R,
    const u16* __restrict__ Vc, void* __restrict__ out)
{
    int row = blockIdx.x;
    size_t roff = (size_t)row * ND;
    int t = threadIdx.x;
    int f = detect_f32((const u16*)Q);
    float v0, v1, v2, v3;
    uint2 ur = ((const uint2*)(R + roff))[t];
    if (f) {
        float4 xq = ((const float4*)Q)[roff / 4 + t];
        v0 = xq.x; v1 = xq.y; v2 = xq.z; v3 = xq.w;
    } else {
        uint2 uq = ((const uint2*)Q)[roff / 4 + t];
        v0 = bf2f(uq.x & 0xffff); v1 = bf2f(uq.x >> 16);
        v2 = bf2f(uq.y & 0xffff); v3 = bf2f(uq.y >> 16);
    }
    v0 += bf2f(ur.x & 0xffff); v1 += bf2f(ur.x >> 16);
    v2 += bf2f(ur.y & 0xffff); v3 += bf2f(ur.y >> 16);
    float s1 = v0 + v1 + v2 + v3;
    float s2 = v0*v0 + v1*v1 + v2*v2 + v3*v3;
#pragma unroll
    for (int off = 32; off >= 1; off >>= 1) {
        s1 += __shfl_xor(s1, off);
        s2 += __shfl_xor(s2, off);
    }
    __shared__ float r1[4], r2[4];
    int wave = t >> 6;
    if ((t & 63) == 0) { r1[wave] = s1; r2[wave] = s2; }
    __syncthreads();
    float t1 = r1[0] + r1[1] + r1[2] + r1[3];
    float t2 = r2[0] + r2[1] + r2[2] + r2[3];
    float mean = t1 * (1.0f / ND);
    float var  = t2 * (1.0f / ND) - mean * mean;
    float rstd = rsqrtf(var + 1e-5f);
    const u16* g  = Vc + 8 * 1024;
    const u16* bb = Vc + 9 * 1024;
    uint2 ug = ((const uint2*)g)[t];
    uint2 ub = ((const uint2*)bb)[t];
    float y0 = (v0 - mean) * rstd * bf2f(ug.x & 0xffff) + bf2f(ub.x & 0xffff);
    float y1 = (v1 - mean) * rstd * bf2f(ug.x >> 16)    + bf2f(ub.x >> 16);
    float y2 = (v2 - mean) * rstd * bf2f(ug.y & 0xffff) + bf2f(ub.y & 0xffff);
    float y3 = (v3 - mean) * rstd * bf2f(ug.y >> 16)    + bf2f(ub.y >> 16);
    if (f) {
        float4 o; o.x = y0; o.y = y1; o.z = y2; o.w = y3;
        ((float4*)out)[roff / 4 + t] = o;
    } else {
        uint2 o;
        o.x = (u32)f2bf(y0) | ((u32)f2bf(y1) << 16);
        o.y = (u32)f2bf(y2) | ((u32)f2bf(y3) << 16);
        ((uint2*)out)[roff / 4 + t] = o;
    }
}

// ---------------------------------------------------------------- launch
extern "C" void kernel_launch(void* const* d_in, const int* in_sizes, int n_in,
                              void* d_out, int out_size, void* d_ws, size_t ws_size,
                              hipStream_t stream) {
    const void* Q        = d_in[0];
    const void* K        = d_in[1];
    const int* pad_mask  = (const int*)d_in[2];

    const size_t NEL = (size_t)NB * NSQ * ND;   // 4,194,304
    int* flag = (int*)d_ws;                      // [0] (unused; layout keep)
    int* cnt  = flag + 1;                        // [1..3)
    int* idx  = flag + 4;                        // [4..4100)
    u16* base = (u16*)(idx + 4096);              // 16-byte aligned
    u16* Qn  = base;
    u16* Kn  = Qn + NEL;
    u16* Q1  = Kn + NEL;
    u16* K1  = Q1 + NEL;                         // COMPACT after gemm4
    u16* Vct = K1 + NEL;                         // TRANSPOSED after gemm4
    u16* R   = Vct + NEL;
    u16* Wc  = R + NEL;
    u16* Vc  = Wc + (size_t)4 * 1024 * 1024;

    prep_kernel<<<dim3(PREP_LN + PREP_CVT + NB), dim3(256), 0, stream>>>(
        Q, K, pad_mask,
        d_in[3], d_in[4], d_in[5], d_in[6],
        d_in[7], d_in[8], d_in[9], d_in[10],
        d_in[11], d_in[12], d_in[13], d_in[14], d_in[15], d_in[16],
        Wc, Vc, idx, cnt, Qn, Kn);

    gemm4_kernel<<<dim3(16, 4, 4), dim3(512), 0, stream>>>(
        Qn, Kn, Wc, Vc, cnt, idx, Q1, K1, Vct, R);

    attn_kernel<<<dim3(NSQ / 64, NH, NB), dim3(256), 0, stream>>>(
        Q1, K1, Vct, cnt, R);

    ln_out_kernel<<<dim3(NB * NSQ), dim3(256), 0, stream>>>(
        Q, R, Vc, d_out);
}

// Round 13
// 204.571 us; speedup vs baseline: 1.8627x; 1.0115x over previous
//
#include <hip/hip_runtime.h>
#include <stdint.h>

#define NB 2
#define NSQ 2048
#define NSK 2048
#define ND 1024
#define NH 16
#define NDH 64

typedef unsigned short u16;
typedef unsigned int u32;
typedef __bf16 bf16x8_t __attribute__((ext_vector_type(8)));
typedef float f32x4_t __attribute__((ext_vector_type(4)));
typedef u32 u32x4_t __attribute__((ext_vector_type(4)));
typedef short s16x4 __attribute__((ext_vector_type(4)));
typedef u32 u32x2_t __attribute__((ext_vector_type(2)));

#define AS1 __attribute__((address_space(1)))
#define AS3 __attribute__((address_space(3)))

__device__ __forceinline__ float bf2f(u16 u) {
    union { float f; u32 i; } v; v.i = ((u32)u) << 16; return v.f;
}
__device__ __forceinline__ u16 f2bf(float x) {
    union { float f; u32 i; } v; v.f = x;
    u32 r = v.i + 0x7fffu + ((v.i >> 16) & 1u);
    return (u16)(r >> 16);
}
__device__ __forceinline__ u32 fbits(float x) {
    union { float f; u32 i; } v; v.f = x; return v.i;
}
__device__ __forceinline__ float fexp2(float x) {
#if __has_builtin(__builtin_amdgcn_exp2f)
    return __builtin_amdgcn_exp2f(x);   // raw v_exp_f32 (base-2)
#else
    return exp2f(x);
#endif
}
// 16x16x16 bf16 MFMA: A/B = 4 bf16 per lane (k = quad*4 + j) — matches the
// QK^T C-fragment key grouping, so P feeds PV with NO cross-lane movement.
__device__ __forceinline__ f32x4_t mfma16(s16x4 a, s16x4 b, f32x4_t c) {
#if __has_builtin(__builtin_amdgcn_mfma_f32_16x16x16bf16_1k)
    return __builtin_amdgcn_mfma_f32_16x16x16bf16_1k(a, b, c, 0, 0, 0);
#else
    asm("v_mfma_f32_16x16x16_bf16 %0, %1, %2, %0" : "+v"(c) : "v"(a), "v"(b));
    return c;
#endif
}
// wave-uniform dtype detect: all lanes read the same first 512B of Q (L2-hot);
// f32 inputs -> low u16s are mantissa bits, virtually surely "exp">=0x8D.
__device__ __forceinline__ int detect_f32(const u16* __restrict__ Q) {
    uint2 x = ((const uint2*)Q)[threadIdx.x & 63];
    u16 a0 = x.x & 0xffff, a1 = x.x >> 16, a2 = x.y & 0xffff, a3 = x.y >> 16;
    bool big = (((a0 >> 7) & 0xff) >= 0x8D) || (((a1 >> 7) & 0xff) >= 0x8D) ||
               (((a2 >> 7) & 0xff) >= 0x8D) || (((a3 >> 7) & 0xff) >= 0x8D);
    return __any(big);   // 1 = f32 inputs, 0 = bf16 inputs (wave-uniform)
}

// ---------------------------------------------------------------- fused prep
// (round-6 verbatim) Block roles by blockIdx.x:
//   [0, 8192)            : input LN  (row = bx); gamma/beta read RAW
//   [8192, 8192+4106)    : param canonicalization (weights + vectors -> bf16)
//   [12298, 12300)       : key index compaction (idx + cnt per batch)
#define PREP_LN   (2 * NB * NSQ)          // 8192
#define PREP_CVT  4106
__global__ __launch_bounds__(256) void prep_kernel(
    const void* __restrict__ Q, const void* __restrict__ K,
    const int* __restrict__ pad_mask,
    const void* __restrict__ Wq, const void* __restrict__ Wk,
    const void* __restrict__ Wv, const void* __restrict__ Wo,
    const void* __restrict__ vbq, const void* __restrict__ vbk,
    const void* __restrict__ vbv, const void* __restrict__ vbo,
    const void* __restrict__ g0, const void* __restrict__ b0,
    const void* __restrict__ g1, const void* __restrict__ b1,
    const void* __restrict__ g2, const void* __restrict__ b2,
    u16* __restrict__ Wc, u16* __restrict__ Vc,
    int* __restrict__ idx, int* __restrict__ cnt,
    u16* __restrict__ Qn, u16* __restrict__ Kn)
{
    int bx = blockIdx.x;
    int t  = threadIdx.x;

    if (bx < PREP_LN) {
        // ---------------- input LN ----------------
        int flag = detect_f32((const u16*)Q);
        int row = bx;
        const void* x; const void *gv, *bv; u16* y;
        size_t roff;
        if (row < NB * NSQ) {
            x = Q; roff = (size_t)row * ND;
            gv = g0; bv = b0;
            y = Qn + roff;
        } else {
            int r2 = row - NB * NSQ;
            x = K; roff = (size_t)r2 * ND;
            gv = g1; bv = b1;
            y = Kn + roff;
        }
        float v0, v1, v2, v3, gg0, gg1, gg2, gg3, bb0, bb1, bb2, bb3;
        if (flag) {
            float4 xv = ((const float4*)x)[roff / 4 + t];
            v0 = xv.x; v1 = xv.y; v2 = xv.z; v3 = xv.w;
            float4 G = ((const float4*)gv)[t];
            float4 Bv = ((const float4*)bv)[t];
            gg0 = G.x; gg1 = G.y; gg2 = G.z; gg3 = G.w;
            bb0 = Bv.x; bb1 = Bv.y; bb2 = Bv.z; bb3 = Bv.w;
        } else {
            uint2 ux = ((const uint2*)x)[roff / 4 + t];
            v0 = bf2f(ux.x & 0xffff); v1 = bf2f(ux.x >> 16);
            v2 = bf2f(ux.y & 0xffff); v3 = bf2f(ux.y >> 16);
            uint2 G = ((const uint2*)gv)[t];
            uint2 Bv = ((const uint2*)bv)[t];
            gg0 = bf2f(G.x & 0xffff); gg1 = bf2f(G.x >> 16);
            gg2 = bf2f(G.y & 0xffff); gg3 = bf2f(G.y >> 16);
            bb0 = bf2f(Bv.x & 0xffff); bb1 = bf2f(Bv.x >> 16);
            bb2 = bf2f(Bv.y & 0xffff); bb3 = bf2f(Bv.y >> 16);
        }
        float s1 = v0 + v1 + v2 + v3;
        float s2 = v0*v0 + v1*v1 + v2*v2 + v3*v3;
#pragma unroll
        for (int off = 32; off >= 1; off >>= 1) {
            s1 += __shfl_xor(s1, off);
            s2 += __shfl_xor(s2, off);
        }
        __shared__ float r1[4], r2[4];
        int wave = t >> 6;
        if ((t & 63) == 0) { r1[wave] = s1; r2[wave] = s2; }
        __syncthreads();
        float t1 = r1[0] + r1[1] + r1[2] + r1[3];
        float t2 = r2[0] + r2[1] + r2[2] + r2[3];
        float mean = t1 * (1.0f / ND);
        float var  = t2 * (1.0f / ND) - mean * mean;
        float rstd = rsqrtf(var + 1e-5f);
        float y0 = (v0 - mean) * rstd * gg0 + bb0;
        float y1 = (v1 - mean) * rstd * gg1 + bb1;
        float y2 = (v2 - mean) * rstd * gg2 + bb2;
        float y3 = (v3 - mean) * rstd * gg3 + bb3;
        uint2 o;
        o.x = (u32)f2bf(y0) | ((u32)f2bf(y1) << 16);
        o.y = (u32)f2bf(y2) | ((u32)f2bf(y3) << 16);
        ((uint2*)y)[t] = o;
    } else if (bx < PREP_LN + PREP_CVT) {
        // ---------------- param canonicalization ----------------
        int flag = detect_f32((const u16*)Q);
        int blk = bx - PREP_LN;
        const void* src;
        u16* dst;
        size_t srcoff;
        if (blk < 4096) {
            int w = blk >> 10;
            src = (w == 0) ? Wq : (w == 1) ? Wk : (w == 2) ? Wv : Wo;
            srcoff = (size_t)(blk & 1023) * 1024;
            dst = Wc + (size_t)w * 1024 * 1024 + srcoff;
        } else {
            int v = blk - 4096;
            src = (v == 0) ? vbq : (v == 1) ? vbk : (v == 2) ? vbv : (v == 3) ? vbo :
                  (v == 4) ? g0  : (v == 5) ? b0  : (v == 6) ? g1  : (v == 7) ? b1 :
                  (v == 8) ? g2  : b2;
            srcoff = 0;
            dst = Vc + (size_t)v * 1024;
        }
        u32 lo, hi;
        if (flag) {
            float4 x = ((const float4*)src)[srcoff / 4 + t];
            lo = (u32)f2bf(x.x) | ((u32)f2bf(x.y) << 16);
            hi = (u32)f2bf(x.z) | ((u32)f2bf(x.w) << 16);
        } else {
            uint2 x = ((const uint2*)src)[srcoff / 4 + t];
            lo = x.x; hi = x.y;
        }
        uint2 o; o.x = lo; o.y = hi;
        ((uint2*)dst)[t] = o;
    } else {
        // ---------------- key index compaction ----------------
        int b = bx - (PREP_LN + PREP_CVT);
        const int* m = pad_mask + b * NSK;
        int loc[8]; int s = 0;
#pragma unroll
        for (int i = 0; i < 8; ++i) { loc[i] = (m[t * 8 + i] != 0); s += loc[i]; }
        __shared__ int ps[256];
        ps[t] = s;
        __syncthreads();
        for (int off = 1; off < 256; off <<= 1) {
            int v = (t >= off) ? ps[t - off] : 0;
            __syncthreads();
            ps[t] += v;
            __syncthreads();
        }
        int run = ps[t] - s;   // exclusive prefix
#pragma unroll
        for (int i = 0; i < 8; ++i)
            if (loc[i]) idx[b * NSK + run++] = t * 8 + i;
        if (t == 255) cnt[b] = ps[255];
    }
}

// ---------------------------------------------------------------- fused 4x GEMM
// (round-12 known-good) 256x256 tile, 8 waves (2M x 4N), BK=32, ring-4 LDS,
// ONE barrier per K-tile, counted vmcnt(8), drain 8->4->0. T2 both-sides
// swizzle; bijective XCD swizzle. Compaction rides the A-addressing for
// z=1/z=2 (idx at prologue only); tail rows clamp to 0; tiles past cPad
// early-exit; z=2 epilogue writes transposed directly to Vct.
// z=0: (Qn@Wq^T+bq)*log2e/32 -> Q1 ; z=1: Kn[idx]@Wk^T+bk -> K1 (compact)
// z=2: Kn[idx]@Wv^T+bv -> Vct (transposed) ; z=3: relu(Qn@Wo^T+bo) -> R
__global__ __launch_bounds__(512, 2) void gemm4_kernel(
    const u16* __restrict__ Qn, const u16* __restrict__ Kn,
    const u16* __restrict__ Wc, const u16* __restrict__ Vc,
    const int* __restrict__ cnt, const int* __restrict__ idx,
    u16* __restrict__ Q1, u16* __restrict__ K1, u16* __restrict__ Vct,
    u16* __restrict__ R)
{
    // XCD-aware remap of (bx,by,bz): lin increments x fastest (dispatch order)
    int lin = blockIdx.x + 16 * blockIdx.y + 64 * blockIdx.z;
    int u   = (lin & 7) * 32 + (lin >> 3);
    int bx  = u & 15;
    int by  = (u >> 4) & 3;
    int z   = u >> 6;

    int kv = (z == 1 || z == 2);
    int batch = bx >> 3;
    int c2 = 0;
    if (kv) {
        c2 = cnt[batch];
        int cPad = (c2 + 63) & ~63;
        if ((bx & 7) * 256 >= cPad) return;         // tile fully past keys
    }

    const u16* X    = (z == 0 || z == 3) ? Qn : Kn;
    const u16* W    = Wc + (size_t)z * 1024 * 1024;
    const u16* bias = Vc + (size_t)z * 1024;

    __shared__ u16 sm[4][2][256 * 32];   // 128 KiB: 4 slots x {A,B} x 16 KiB

    int tid  = threadIdx.x;
    int wave = tid >> 6, lane = tid & 63;
    int wm = wave >> 2, wn = wave & 3;          // 2M x 4N wave grid
    int quad = lane >> 4, l4 = lane & 15;
    int m0 = bx * 256;
    int n0 = by * 256;

    // staging: linear LDS dest (gload_lds requirement), pre-swizzled source.
    // Swizzle is keyed to the LDS DEST row -> valid for remapped source rows.
    int srow   = wave * 16 + (lane >> 2);                // dest rows (inst0)
    int schunk = (lane & 3) ^ ((srow >> 1) & 3);         // inv-swizzle source
    const u16 *gA0, *gA1;
    if (kv) {
        int jg0 = (bx & 7) * 256 + srow;                 // compacted key index
        int jg1 = jg0 + 128;
        int ar0 = (jg0 < c2) ? idx[batch * NSK + jg0] : 0;
        int ar1 = (jg1 < c2) ? idx[batch * NSK + jg1] : 0;
        gA0 = Kn + ((size_t)batch * NSK + ar0) * ND + schunk * 8;
        gA1 = Kn + ((size_t)batch * NSK + ar1) * ND + schunk * 8;
    } else {
        gA0 = X + (size_t)(m0 + srow) * ND + schunk * 8;
        gA1 = gA0 + (size_t)128 * ND;
    }
    const u16* gB = W + (size_t)(n0 + srow) * ND + schunk * 8;

#define STAGE_A(t_) do { int s_ = (t_) & 3; \
    __builtin_amdgcn_global_load_lds((const AS1 u32*)(gA0 + (t_) * 32), \
        (AS3 u32*)(&sm[s_][0][wave * 512]), 16, 0, 0); \
    __builtin_amdgcn_global_load_lds((const AS1 u32*)(gA1 + (t_) * 32), \
        (AS3 u32*)(&sm[s_][0][4096 + wave * 512]), 16, 0, 0); \
} while (0)
#define STAGE_B(t_) do { int s_ = (t_) & 3; \
    __builtin_amdgcn_global_load_lds((const AS1 u32*)(gB + (t_) * 32), \
        (AS3 u32*)(&sm[s_][1][wave * 512]), 16, 0, 0); \
    __builtin_amdgcn_global_load_lds((const AS1 u32*)(gB + (t_) * 32 + (size_t)128 * ND), \
        (AS3 u32*)(&sm[s_][1][4096 + wave * 512]), 16, 0, 0); \
} while (0)

    // fragment read addressing; swizzled chunk is lane-constant:
    // row = 16*base + l4  ->  (row>>1)&3 == (l4>>1)&3
    int fch   = (quad ^ ((l4 >> 1) & 3)) * 8;
    int aoffb = (wm * 128 + l4) * 32 + fch;   // + mf*512
    int boffb = (wn * 64  + l4) * 32 + fch;   // + nf*512

    f32x4_t acc[8][4];
#pragma unroll
    for (int i = 0; i < 8; ++i)
#pragma unroll
        for (int j = 0; j < 4; ++j)
            acc[i][j] = (f32x4_t){0.f, 0.f, 0.f, 0.f};

    // prologue: 3 K-tiles in flight, validate tile 0 (8 loads may stay out)
    STAGE_A(0); STAGE_B(0);
    STAGE_A(1); STAGE_B(1);
    STAGE_A(2); STAGE_B(2);
    asm volatile("s_waitcnt vmcnt(8)" ::: "memory");
    __builtin_amdgcn_s_barrier();
    __builtin_amdgcn_sched_barrier(0);

    for (int t = 0; t < 32; ++t) {
        const u16* a = &sm[t & 3][0][0];
        const u16* b = &sm[t & 3][1][0];
        bf16x8_t bf[4], af[4], ah[4];

        // 12 ds_read_b128 (tile t) — compiler interleaves with MFMA via lgkmcnt
#pragma unroll
        for (int nf = 0; nf < 4; ++nf)
            bf[nf] = *(const bf16x8_t*)(b + boffb + nf * 512);
#pragma unroll
        for (int mf = 0; mf < 4; ++mf)
            af[mf] = *(const bf16x8_t*)(a + aoffb + mf * 512);
#pragma unroll
        for (int mf = 0; mf < 4; ++mf)
            ah[mf] = *(const bf16x8_t*)(a + aoffb + (mf + 4) * 512);

        // stage tile t+3 into slot (t-1)&3 (WAR-safe past last barrier)
        if (t < 29) { STAGE_A(t + 3); STAGE_B(t + 3); }

        __builtin_amdgcn_s_setprio(1);
#pragma unroll
        for (int mf = 0; mf < 4; ++mf)
#pragma unroll
            for (int nf = 0; nf < 4; ++nf)
                acc[mf][nf] = __builtin_amdgcn_mfma_f32_16x16x32_bf16(
                    af[mf], bf[nf], acc[mf][nf], 0, 0, 0);
#pragma unroll
        for (int mf = 0; mf < 4; ++mf)
#pragma unroll
            for (int nf = 0; nf < 4; ++nf)
                acc[mf + 4][nf] = __builtin_amdgcn_mfma_f32_16x16x32_bf16(
                    ah[mf], bf[nf], acc[mf + 4][nf], 0, 0, 0);
        __builtin_amdgcn_s_setprio(0);

        // K-tile boundary: validate tile t+1; keep tiles t+2,t+3 in flight
        if (t < 29)       asm volatile("s_waitcnt vmcnt(8)" ::: "memory");
        else if (t == 29) asm volatile("s_waitcnt vmcnt(4)" ::: "memory");
        else if (t == 30) asm volatile("s_waitcnt vmcnt(0)" ::: "memory");
        __builtin_amdgcn_s_barrier();
        __builtin_amdgcn_sched_barrier(0);
    }
#undef STAGE_A
#undef STAGE_B

    float bv_[4];
#pragma unroll
    for (int nf = 0; nf < 4; ++nf)
        bv_[nf] = bf2f(bias[n0 + wn * 64 + nf * 16 + l4]);

    if (z == 2) {
        // transposed epilogue: Vct[(batch*1024 + n) * NSK + j]  (h*64+d == n)
        int jb = (bx & 7) * 256 + wm * 128;
#pragma unroll
        for (int nf = 0; nf < 4; ++nf) {
            int n = n0 + wn * 64 + nf * 16 + l4;
            float bvv = bv_[nf];
            u16* rowp = Vct + ((size_t)batch * 1024 + n) * NSK;
#pragma unroll
            for (int mf = 0; mf < 8; ++mf) {
                int j = jb + mf * 16 + quad * 4;
                uint2 o;
                o.x = (u32)f2bf(acc[mf][nf][0] + bvv)
                    | ((u32)f2bf(acc[mf][nf][1] + bvv) << 16);
                o.y = (u32)f2bf(acc[mf][nf][2] + bvv)
                    | ((u32)f2bf(acc[mf][nf][3] + bvv) << 16);
                *(uint2*)(rowp + j) = o;
            }
        }
        return;
    }

    // epilogue (z=0,1,3): mf/r outer, nf inner -> line-complete store order
    u16* outp = (z == 0) ? Q1 : (z == 1) ? K1 : R;
#pragma unroll
    for (int mf = 0; mf < 8; ++mf) {
#pragma unroll
        for (int r = 0; r < 4; ++r) {
            int m = m0 + wm * 128 + mf * 16 + quad * 4 + r;
#pragma unroll
            for (int nf = 0; nf < 4; ++nf) {
                int n = n0 + wn * 64 + nf * 16 + l4;
                float val = acc[mf][nf][r] + bv_[nf];
                if (z == 0) val *= 0.045105964f;   // (1/32) * log2(e)
                if (z == 3) val = fmaxf(val, 0.f);
                outp[(size_t)m * ND + n] = f2bf(val);
            }
        }
    }
}

// ---------------------------------------------------------------- flash attention
// QBLK=128: each block handles TWO 64-row q-groups (g=0,1). K/V staging per
// tile is unchanged -> staging + barriers amortize over 2x MFMA work; K and
// V LDS fragments are read ONCE and reused by both groups. lsum cross-lane
// reduce hoisted out of the K-loop (linear). Tail keys masked by -1e9 C-init.
__global__ __launch_bounds__(256, 4) void attn_kernel(
    const u16* __restrict__ Q1, const u16* __restrict__ K1c,
    const u16* __restrict__ Vct, const int* __restrict__ cnt,
    u16* __restrict__ R)
{
    int q0 = blockIdx.x * 128;
    int h  = blockIdx.y;
    int b  = blockIdx.z;

    __shared__ u16 sK[2][64 * 64];
    __shared__ u16 sV[2][64 * 64];

    int tid  = threadIdx.x;
    int wave = tid >> 6, lane = tid & 63;
    int quad = lane >> 4, l4 = lane & 15;
    int lk = lane >> 3, ls = lane & 7;
    int gseg = ls ^ lk;

    int c  = cnt[b];
    int nt = (c + 63) >> 6;

    bf16x8_t qf[2][2];
#pragma unroll
    for (int g = 0; g < 2; ++g) {
        const u16* qp = Q1 +
            (size_t)(b * NSQ + q0 + g * 64 + wave * 16 + l4) * ND + h * NDH;
        qf[g][0] = *(const bf16x8_t*)(qp + quad * 8);
        qf[g][1] = *(const bf16x8_t*)(qp + 32 + quad * 8);
    }

    const u16* kbase = K1c + (size_t)b * NSK * ND + h * NDH;
    const u16* vbase = Vct + (size_t)(b * NH + h) * NDH * NSK;

    const u16* gk0 = kbase + (size_t)(wave * 16 + lk) * ND + gseg * 8;
    const u16* gk1 = gk0 + (size_t)8 * ND;
    const u16* gv0 = vbase + (size_t)(wave * 16 + lk) * NSK + gseg * 8;
    const u16* gv1 = gv0 + (size_t)8 * NSK;

    // K-fragment (x32) swizzled offsets
    int fragOff[2];
#pragma unroll
    for (int kk = 0; kk < 2; ++kk)
        fragOff[kk] = l4 * 64 + (((kk * 4 + quad) ^ (l4 & 7)) * 8);

    // V-fragment (x16) swizzled offsets: keys 16*tm + 4*quad + j, row l4
    int v4off[4];
#pragma unroll
    for (int tm = 0; tm < 4; ++tm)
        v4off[tm] = l4 * 64 + (((2 * tm + (quad >> 1)) ^ (l4 & 7)) * 8)
                  + (quad & 1) * 4;

    float l_run[2] = {0.f, 0.f};
    f32x4_t acc_o[2][4];
#pragma unroll
    for (int g = 0; g < 2; ++g)
#pragma unroll
        for (int T = 0; T < 4; ++T)
            acc_o[g][T] = (f32x4_t){0.f, 0.f, 0.f, 0.f};

    if (nt > 0) {
        __builtin_amdgcn_global_load_lds((const AS1 u32*)gk0,
            (AS3 u32*)(&sK[0][(wave * 16) * 64]), 16, 0, 0);
        __builtin_amdgcn_global_load_lds((const AS1 u32*)gk1,
            (AS3 u32*)(&sK[0][(wave * 16 + 8) * 64]), 16, 0, 0);
        __builtin_amdgcn_global_load_lds((const AS1 u32*)gv0,
            (AS3 u32*)(&sV[0][(wave * 16) * 64]), 16, 0, 0);
        __builtin_amdgcn_global_load_lds((const AS1 u32*)gv1,
            (AS3 u32*)(&sV[0][(wave * 16 + 8) * 64]), 16, 0, 0);
        gk0 += (size_t)64 * ND; gk1 += (size_t)64 * ND;
        gv0 += 64; gv1 += 64;

        for (int kb = 0; kb < nt; ++kb) {
            __syncthreads();

            if (kb + 1 < nt) {
                int bi = (kb + 1) & 1;
                __builtin_amdgcn_global_load_lds((const AS1 u32*)gk0,
                    (AS3 u32*)(&sK[bi][(wave * 16) * 64]), 16, 0, 0);
                __builtin_amdgcn_global_load_lds((const AS1 u32*)gk1,
                    (AS3 u32*)(&sK[bi][(wave * 16 + 8) * 64]), 16, 0, 0);
                __builtin_amdgcn_global_load_lds((const AS1 u32*)gv0,
                    (AS3 u32*)(&sV[bi][(wave * 16) * 64]), 16, 0, 0);
                __builtin_amdgcn_global_load_lds((const AS1 u32*)gv1,
                    (AS3 u32*)(&sV[bi][(wave * 16 + 8) * 64]), 16, 0, 0);
                gk0 += (size_t)64 * ND; gk1 += (size_t)64 * ND;
                gv0 += 64; gv1 += 64;
            }

            const u16* kt = sK[kb & 1];
            const u16* vt = sV[kb & 1];

            // C-init: 0 for valid keys; -1e9 on tail keys >= cnt (same both g)
            f32x4_t accs[2][4];
            if (kb == nt - 1) {
#pragma unroll
                for (int tm = 0; tm < 4; ++tm) {
                    int key = kb * 64 + tm * 16 + quad * 4;
#pragma unroll
                    for (int r = 0; r < 4; ++r) {
                        float ci = (key + r < c) ? 0.f : -1e9f;
                        accs[0][tm][r] = ci;
                        accs[1][tm][r] = ci;
                    }
                }
            } else {
#pragma unroll
                for (int g = 0; g < 2; ++g)
#pragma unroll
                    for (int tm = 0; tm < 4; ++tm)
                        accs[g][tm] = (f32x4_t){0.f, 0.f, 0.f, 0.f};
            }
            // QK^T: each K-fragment read once, used by both q-groups
#pragma unroll
            for (int kk = 0; kk < 2; ++kk)
#pragma unroll
                for (int tm = 0; tm < 4; ++tm) {
                    bf16x8_t kf = *(const bf16x8_t*)(kt + tm * 1024 + fragOff[kk]);
                    accs[0][tm] = __builtin_amdgcn_mfma_f32_16x16x32_bf16(
                        kf, qf[0][kk], accs[0][tm], 0, 0, 0);
                    accs[1][tm] = __builtin_amdgcn_mfma_f32_16x16x32_bf16(
                        kf, qf[1][kk], accs[1][tm], 0, 0, 0);
                }

            // softmax + PV fused: V-fragments read once, used by both groups
#pragma unroll
            for (int tm = 0; tm < 4; ++tm) {
                s16x4 vf0 = *(const s16x4*)(vt + 0 * 1024 + v4off[tm]);
                s16x4 vf1 = *(const s16x4*)(vt + 1 * 1024 + v4off[tm]);
                s16x4 vf2 = *(const s16x4*)(vt + 2 * 1024 + v4off[tm]);
                s16x4 vf3 = *(const s16x4*)(vt + 3 * 1024 + v4off[tm]);
#pragma unroll
                for (int g = 0; g < 2; ++g) {
                    float p0 = fexp2(accs[g][tm][0]);
                    float p1 = fexp2(accs[g][tm][1]);
                    float p2 = fexp2(accs[g][tm][2]);
                    float p3 = fexp2(accs[g][tm][3]);
                    l_run[g] += (p0 + p1) + (p2 + p3);
                    u32 lo = __builtin_amdgcn_perm(fbits(p1), fbits(p0), 0x07060302);
                    u32 hi = __builtin_amdgcn_perm(fbits(p3), fbits(p2), 0x07060302);
                    s16x4 pf = __builtin_bit_cast(s16x4, (u32x2_t){lo, hi});
                    acc_o[g][0] = mfma16(vf0, pf, acc_o[g][0]);
                    acc_o[g][1] = mfma16(vf1, pf, acc_o[g][1]);
                    acc_o[g][2] = mfma16(vf2, pf, acc_o[g][2]);
                    acc_o[g][3] = mfma16(vf3, pf, acc_o[g][3]);
                }
            }
        }
    }

    // epilogue: cross-lane lsum reduce (hoisted; linear in tiles),
    // then O[q][d] = acc_o / l ; R += O1 (uint2 RMW)
#pragma unroll
    for (int g = 0; g < 2; ++g) {
        float ls = l_run[g];
        ls += __shfl_xor(ls, 16);
        ls += __shfl_xor(ls, 32);
        float inv = ls > 0.f ? 1.f / ls : 0.f;
        u16* rp = R + (size_t)(b * NSQ + q0 + g * 64 + wave * 16 + l4) * ND + h * NDH;
#pragma unroll
        for (int T = 0; T < 4; ++T) {
            u16* p = rp + T * 16 + quad * 4;
            uint2 o2 = *(const uint2*)p;
            float e0 = acc_o[g][T][0] * inv + bf2f(o2.x & 0xffff);
            float e1 = acc_o[g][T][1] * inv + bf2f(o2.x >> 16);
            float e2 = acc_o[g][T][2] * inv + bf2f(o2.y & 0xffff);
            float e3 = acc_o[g][T][3] * inv + bf2f(o2.y >> 16);
            uint2 on;
            on.x = (u32)f2bf(e0) | ((u32)f2bf(e1) << 16);
            on.y = (u32)f2bf(e2) | ((u32)f2bf(e3) << 16);
            *(uint2*)p = on;
        }
    }
}

// ---------------------------------------------------------------- final LN
__global__ __launch_bounds__(256) void ln_out_kernel(
    const void* __restrict__ Q, const u16* __restrict__ R,
    const u16* __restrict__ Vc, void* __restrict__ out)
{
    int row = blockIdx.x;
    size_t roff = (size_t)row * ND;
    int t = threadIdx.x;
    int f = detect_f32((const u16*)Q);
    float v0, v1, v2, v3;
    uint2 ur = ((const uint2*)(R + roff))[t];
    if (f) {
        float4 xq = ((const float4*)Q)[roff / 4 + t];
        v0 = xq.x; v1 = xq.y; v2 = xq.z; v3 = xq.w;
    } else {
        uint2 uq = ((const uint2*)Q)[roff / 4 + t];
        v0 = bf2f(uq.x & 0xffff); v1 = bf2f(uq.x >> 16);
        v2 = bf2f(uq.y & 0xffff); v3 = bf2f(uq.y >> 16);
    }
    v0 += bf2f(ur.x & 0xffff); v1 += bf2f(ur.x >> 16);
    v2 += bf2f(ur.y & 0xffff); v3 += bf2f(ur.y >> 16);
    float s1 = v0 + v1 + v2 + v3;
    float s2 = v0*v0 + v1*v1 + v2*v2 + v3*v3;
#pragma unroll
    for (int off = 32; off >= 1; off >>= 1) {
        s1 += __shfl_xor(s1, off);
        s2 += __shfl_xor(s2, off);
    }
    __shared__ float r1[4], r2[4];
    int wave = t >> 6;
    if ((t & 63) == 0) { r1[wave] = s1; r2[wave] = s2; }
    __syncthreads();
    float t1 = r1[0] + r1[1] + r1[2] + r1[3];
    float t2 = r2[0] + r2[1] + r2[2] + r2[3];
    float mean = t1 * (1.0f / ND);
    float var  = t2 * (1.0f / ND) - mean * mean;
    float rstd = rsqrtf(var + 1e-5f);
    const u16* g  = Vc + 8 * 1024;
    const u16* bb = Vc + 9 * 1024;
    uint2 ug = ((const uint2*)g)[t];
    uint2 ub = ((const uint2*)bb)[t];
    float y0 = (v0 - mean) * rstd * bf2f(ug.x & 0xffff) + bf2f(ub.x & 0xffff);
    float y1 = (v1 - mean) * rstd * bf2f(ug.x >> 16)    + bf2f(ub.x >> 16);
    float y2 = (v2 - mean) * rstd * bf2f(ug.y & 0xffff) + bf2f(ub.y & 0xffff);
    float y3 = (v3 - mean) * rstd * bf2f(ug.y >> 16)    + bf2f(ub.y >> 16);
    if (f) {
        float4 o; o.x = y0; o.y = y1; o.z = y2; o.w = y3;
        ((float4*)out)[roff / 4 + t] = o;
    } else {
        uint2 o;
        o.x = (u32)f2bf(y0) | ((u32)f2bf(y1) << 16);
        o.y = (u32)f2bf(y2) | ((u32)f2bf(y3) << 16);
        ((uint2*)out)[roff / 4 + t] = o;
    }
}

// ---------------------------------------------------------------- launch
extern "C" void kernel_launch(void* const* d_in, const int* in_sizes, int n_in,
                              void* d_out, int out_size, void* d_ws, size_t ws_size,
                              hipStream_t stream) {
    const void* Q        = d_in[0];
    const void* K        = d_in[1];
    const int* pad_mask  = (const int*)d_in[2];

    const size_t NEL = (size_t)NB * NSQ * ND;   // 4,194,304
    int* flag = (int*)d_ws;                      // [0] (unused; layout keep)
    int* cnt  = flag + 1;                        // [1..3)
    int* idx  = flag + 4;                        // [4..4100)
    u16* base = (u16*)(idx + 4096);              // 16-byte aligned
    u16* Qn  = base;
    u16* Kn  = Qn + NEL;
    u16* Q1  = Kn + NEL;
    u16* K1  = Q1 + NEL;                         // COMPACT after gemm4
    u16* Vct = K1 + NEL;                         // TRANSPOSED after gemm4
    u16* R   = Vct + NEL;
    u16* Wc  = R + NEL;
    u16* Vc  = Wc + (size_t)4 * 1024 * 1024;

    prep_kernel<<<dim3(PREP_LN + PREP_CVT + NB), dim3(256), 0, stream>>>(
        Q, K, pad_mask,
        d_in[3], d_in[4], d_in[5], d_in[6],
        d_in[7], d_in[8], d_in[9], d_in[10],
        d_in[11], d_in[12], d_in[13], d_in[14], d_in[15], d_in[16],
        Wc, Vc, idx, cnt, Qn, Kn);

    gemm4_kernel<<<dim3(16, 4, 4), dim3(512), 0, stream>>>(
        Qn, Kn, Wc, Vc, cnt, idx, Q1, K1, Vct, R);

    attn_kernel<<<dim3(NSQ / 128, NH, NB), dim3(256), 0, stream>>>(
        Q1, K1, Vct, cnt, R);

    ln_out_kernel<<<dim3(NB * NSQ), dim3(256), 0, stream>>>(
        Q, R, Vc, d_out);
}